// Round 2
// baseline (3590.814 us; speedup 1.0000x reference)
//
#include <hip/hip_runtime.h>
#include <hip/hip_bf16.h>
#include <math.h>

#define NN 50000
#define EE 800000
#define HH 128
#define FF 128
#define GG 50
#define LL 6
#define H2D 64
#define OUT_DIM 12

typedef __bf16 bf16;
typedef __attribute__((ext_vector_type(8))) __bf16 bf16x8;
typedef __attribute__((ext_vector_type(4))) float f32x4;

#define DEV __device__ __forceinline__

DEV float sspf(float x) {
    // softplus(x) - ln2, numerically stable
    return fmaxf(x, 0.f) + log1pf(__expf(-fabsf(x))) - 0.69314718055994531f;
}

DEV f32x4 mfma16(bf16x8 a, bf16x8 b, f32x4 c) {
    return __builtin_amdgcn_mfma_f32_16x16x32_bf16(a, b, c, 0, 0, 0);
}

// -------- prep: transpose all f32 weights to [n][k] bf16, K zero-padded ------
struct PrepArgs {
    const float *mlp_w1, *mlp_w2, *conv1_w, *conv2_w, *int_lin_w, *lin1_w, *lin2_w;
    bf16 *w1t, *w2t, *c1t, *c2t, *ilt, *l1t, *l2t;
};

__global__ void prep_kernel(PrepArgs p) {
    int j = blockIdx.x;
    const float* src = nullptr; bf16* dst = nullptr; int R = 0, C = 0, K = 0;
    if (j < 30) {
        int l = j / 5, m = j % 5;
        switch (m) {
            case 0: src = p.mlp_w1 + l * GG * FF;  dst = p.w1t + l * FF * 64;  R = GG; C = FF;  K = 64;  break;
            case 1: src = p.mlp_w2 + l * FF * FF;  dst = p.w2t + l * FF * FF;  R = FF; C = FF;  K = FF;  break;
            case 2: src = p.conv1_w + l * HH * FF; dst = p.c1t + l * FF * HH;  R = HH; C = FF;  K = HH;  break;
            case 3: src = p.conv2_w + l * FF * HH; dst = p.c2t + l * HH * FF;  R = FF; C = HH;  K = FF;  break;
            case 4: src = p.int_lin_w + l * HH * HH; dst = p.ilt + l * HH * HH; R = HH; C = HH; K = HH;  break;
        }
    } else if (j == 30) { src = p.lin1_w; dst = p.l1t; R = HH;  C = H2D; K = HH; }
    else               { src = p.lin2_w; dst = p.l2t; R = H2D; C = H2D; K = H2D; }
    int total = C * K;
    for (int idx = threadIdx.x; idx < total; idx += blockDim.x) {
        int c = idx / K, r = idx - c * K;
        dst[idx] = (r < R) ? (bf16)src[r * C + c] : (bf16)0.f;
    }
}

// -------- embed: h = embedding[x_atoms] (f32 + bf16 copies) ------------------
__global__ void embed_kernel(const int* __restrict__ x_atoms, const float* __restrict__ emb,
                             float* __restrict__ h, bf16* __restrict__ hb) {
    int idx = blockIdx.x * blockDim.x + threadIdx.x;   // over NN*16
    if (idx >= NN * 16) return;
    int n = idx >> 4, ch = idx & 15;
    int a = x_atoms[n];
    const float* ep = emb + a * HH + ch * 8;
    f32x4 v0 = *(const f32x4*)ep;
    f32x4 v1 = *(const f32x4*)(ep + 4);
    float* hp = h + n * HH + ch * 8;
    bf16* hbp = hb + n * HH + ch * 8;
    bf16x8 vb;
#pragma unroll
    for (int q = 0; q < 4; q++) {
        hp[q] = v0[q]; hp[q + 4] = v1[q];
        vb[q] = (bf16)v0[q]; vb[q + 4] = (bf16)v1[q];
    }
    *(bf16x8*)hbp = vb;
}

// -------- xf = h @ conv1_w  (bf16 out) ---------------------------------------
__global__ __launch_bounds__(256) void xf_kernel(const bf16* __restrict__ hb,
                                                 const bf16* __restrict__ c1t,
                                                 bf16* __restrict__ xf) {
    __shared__ bf16 sB[128 * 136];
    int tid = threadIdx.x;
    for (int idx = tid * 8; idx < 128 * 128; idx += 2048) {
        int n = idx >> 7, k = idx & 127;
        *(bf16x8*)&sB[n * 136 + k] = *(const bf16x8*)(c1t + idx);
    }
    int w = tid >> 6, lane = tid & 63, ln = lane & 15, kg = lane >> 4;
    int rowt = blockIdx.x * 64 + w * 16;
    int arow = min(rowt + ln, NN - 1);
    __syncthreads();
    f32x4 acc[8] = {};
#pragma unroll
    for (int k0 = 0; k0 < 128; k0 += 32) {
        bf16x8 a = *(const bf16x8*)(hb + arow * HH + k0 + kg * 8);
#pragma unroll
        for (int t = 0; t < 8; t++) {
            bf16x8 b = *(const bf16x8*)&sB[(t * 16 + ln) * 136 + k0 + kg * 8];
            acc[t] = mfma16(a, b, acc[t]);
        }
    }
#pragma unroll
    for (int t = 0; t < 8; t++) {
        int colt = t * 16 + ln;
#pragma unroll
        for (int r = 0; r < 4; r++) {
            int orow = rowt + kg * 4 + r;
            if (orow < NN) xf[orow * FF + colt] = (bf16)acc[t][r];
        }
    }
}

// -------- fused edge kernel --------------------------------------------------
__global__ __launch_bounds__(256) void edge_kernel(const float* __restrict__ eattr,
                                                   const int* __restrict__ eidx,
                                                   const bf16* __restrict__ xf,
                                                   const bf16* __restrict__ w1t,
                                                   const bf16* __restrict__ w2t,
                                                   const float* __restrict__ b1,
                                                   const float* __restrict__ b2,
                                                   float* __restrict__ agg) {
    __shared__ bf16 sW2[128 * 136];   // 34816 B
    __shared__ bf16 sW1[128 * 72];    // 18432 B, aliased later as sXf[64*136]
    __shared__ bf16 sT1[64 * 136];    // 17408 B
    int tid = threadIdx.x;
    int eb = blockIdx.x * 64;
    // stage W1T [128n][64k] and W2T [128n][128k]
    for (int idx = tid * 8; idx < 128 * 64; idx += 2048) {
        int n = idx >> 6, k = idx & 63;
        *(bf16x8*)&sW1[n * 72 + k] = *(const bf16x8*)(w1t + idx);
    }
    for (int idx = tid * 8; idx < 128 * 128; idx += 2048) {
        int n = idx >> 7, k = idx & 127;
        *(bf16x8*)&sW2[n * 136 + k] = *(const bf16x8*)(w2t + idx);
    }
    int w = tid >> 6, lane = tid & 63, ln = lane & 15, kg = lane >> 4;
    float d1 = eattr[eb + w * 16 + ln];
    const float step = 10.f / 49.f;
    const float coeff = -0.5f / (step * step);
    __syncthreads();
    // GEMM1: ed(in-register gaussians) @ W1  (wave strip = 16 edges)
    f32x4 acc[8] = {};
#pragma unroll
    for (int k0 = 0; k0 < 64; k0 += 32) {
        bf16x8 a;
#pragma unroll
        for (int jj = 0; jj < 8; jj++) {
            int g = k0 + kg * 8 + jj;
            float diff = d1 - g * step;
            float v = (g < GG) ? __expf(coeff * diff * diff) : 0.f;
            a[jj] = (bf16)v;
        }
#pragma unroll
        for (int t = 0; t < 8; t++) {
            bf16x8 b = *(const bf16x8*)&sW1[(t * 16 + ln) * 72 + k0 + kg * 8];
            acc[t] = mfma16(a, b, acc[t]);
        }
    }
    // + b1, ssp, C->A layout via LDS
#pragma unroll
    for (int t = 0; t < 8; t++) {
        int colt = t * 16 + ln;
        float bb = b1[colt];
#pragma unroll
        for (int r = 0; r < 4; r++)
            sT1[(w * 16 + kg * 4 + r) * 136 + colt] = (bf16)sspf(acc[t][r] + bb);
    }
    __syncthreads();   // GEMM1 reads of sW1 done; sT1 visible
    // gather xf[src] rows into sXf (aliases sW1)
    bf16* sXf = sW1;
    for (int c = tid; c < 64 * 16; c += 256) {
        int row = c >> 4, ch = c & 15;
        int s = eidx[eb + row];
        *(bf16x8*)&sXf[row * 136 + ch * 8] = *(const bf16x8*)(xf + s * FF + ch * 8);
    }
    // GEMM2: t1 @ W2
    f32x4 acc2[8] = {};
#pragma unroll
    for (int k0 = 0; k0 < 128; k0 += 32) {
        bf16x8 a = *(const bf16x8*)&sT1[(w * 16 + ln) * 136 + k0 + kg * 8];
#pragma unroll
        for (int t = 0; t < 8; t++) {
            bf16x8 b = *(const bf16x8*)&sW2[(t * 16 + ln) * 136 + k0 + kg * 8];
            acc2[t] = mfma16(a, b, acc2[t]);
        }
    }
    __syncthreads();   // sXf visible
    // epilogue: (acc2 + b2) * C(d) * xf[src]  -> atomic scatter into agg[dst]
    float Cw[4]; int dstn[4]; int drow[4];
#pragma unroll
    for (int r = 0; r < 4; r++) {
        int lr = w * 16 + kg * 4 + r;
        drow[r] = lr;
        float dd = eattr[eb + lr];
        Cw[r] = 0.5f * (cosf(dd * 0.31415926535f) + 1.f);
        dstn[r] = eidx[EE + eb + lr];
    }
#pragma unroll
    for (int t = 0; t < 8; t++) {
        int colt = t * 16 + ln;
        float b2v = b2[colt];
#pragma unroll
        for (int r = 0; r < 4; r++) {
            float val = (acc2[t][r] + b2v) * Cw[r];
            float xv = (float)sXf[drow[r] * 136 + colt];
            unsafeAtomicAdd(&agg[dstn[r] * FF + colt], val * xv);
        }
    }
}

// -------- update: h += (ssp(agg@conv2+b) @ int_lin + b) ----------------------
__global__ __launch_bounds__(256) void update_kernel(const float* __restrict__ agg,
                                                     const bf16* __restrict__ c2t,
                                                     const float* __restrict__ c2b,
                                                     const bf16* __restrict__ ilt,
                                                     const float* __restrict__ ilb,
                                                     float* __restrict__ h,
                                                     bf16* __restrict__ hb) {
    __shared__ bf16 sB1[128 * 136];
    __shared__ bf16 sB2[128 * 136];
    __shared__ bf16 sT[64 * 136];
    int tid = threadIdx.x;
    for (int idx = tid * 8; idx < 128 * 128; idx += 2048) {
        int n = idx >> 7, k = idx & 127;
        *(bf16x8*)&sB1[n * 136 + k] = *(const bf16x8*)(c2t + idx);
        *(bf16x8*)&sB2[n * 136 + k] = *(const bf16x8*)(ilt + idx);
    }
    int w = tid >> 6, lane = tid & 63, ln = lane & 15, kg = lane >> 4;
    int rowt = blockIdx.x * 64 + w * 16;
    int arow = min(rowt + ln, NN - 1);
    __syncthreads();
    f32x4 acc[8] = {};
#pragma unroll
    for (int k0 = 0; k0 < 128; k0 += 32) {
        const float* ap = agg + arow * FF + k0 + kg * 8;
        f32x4 u0 = *(const f32x4*)ap;
        f32x4 u1 = *(const f32x4*)(ap + 4);
        bf16x8 a;
#pragma unroll
        for (int q = 0; q < 4; q++) { a[q] = (bf16)u0[q]; a[q + 4] = (bf16)u1[q]; }
#pragma unroll
        for (int t = 0; t < 8; t++) {
            bf16x8 b = *(const bf16x8*)&sB1[(t * 16 + ln) * 136 + k0 + kg * 8];
            acc[t] = mfma16(a, b, acc[t]);
        }
    }
#pragma unroll
    for (int t = 0; t < 8; t++) {
        int colt = t * 16 + ln;
        float bb = c2b[colt];
#pragma unroll
        for (int r = 0; r < 4; r++)
            sT[(w * 16 + kg * 4 + r) * 136 + colt] = (bf16)sspf(acc[t][r] + bb);
    }
    __syncthreads();
    f32x4 acc2[8] = {};
#pragma unroll
    for (int k0 = 0; k0 < 128; k0 += 32) {
        bf16x8 a = *(const bf16x8*)&sT[(w * 16 + ln) * 136 + k0 + kg * 8];
#pragma unroll
        for (int t = 0; t < 8; t++) {
            bf16x8 b = *(const bf16x8*)&sB2[(t * 16 + ln) * 136 + k0 + kg * 8];
            acc2[t] = mfma16(a, b, acc2[t]);
        }
    }
#pragma unroll
    for (int t = 0; t < 8; t++) {
        int colt = t * 16 + ln;
        float bb = ilb[colt];
#pragma unroll
        for (int r = 0; r < 4; r++) {
            int orow = rowt + kg * 4 + r;
            if (orow < NN) {
                float nh = h[orow * HH + colt] + acc2[t][r] + bb;
                h[orow * HH + colt] = nh;
                hb[orow * HH + colt] = (bf16)nh;
            }
        }
    }
}

// -------- head: sum over nodes of (ssp(h@lin1+b)@lin2+b) ---------------------
__global__ __launch_bounds__(256) void head_kernel(const bf16* __restrict__ hb,
                                                   const bf16* __restrict__ l1t,
                                                   const float* __restrict__ l1b,
                                                   const bf16* __restrict__ l2t,
                                                   const float* __restrict__ l2b,
                                                   float* __restrict__ sumvec) {
    __shared__ bf16 sB1[64 * 136];
    __shared__ bf16 sB2[64 * 72];
    __shared__ bf16 sT[64 * 72];
    int tid = threadIdx.x;
    for (int idx = tid * 8; idx < 64 * 128; idx += 2048) {
        int n = idx >> 7, k = idx & 127;
        *(bf16x8*)&sB1[n * 136 + k] = *(const bf16x8*)(l1t + idx);
    }
    for (int idx = tid * 8; idx < 64 * 64; idx += 2048) {
        int n = idx >> 6, k = idx & 63;
        *(bf16x8*)&sB2[n * 72 + k] = *(const bf16x8*)(l2t + idx);
    }
    int w = tid >> 6, lane = tid & 63, ln = lane & 15, kg = lane >> 4;
    int rowt = blockIdx.x * 64 + w * 16;
    int arow = min(rowt + ln, NN - 1);
    __syncthreads();
    f32x4 acc[4] = {};
#pragma unroll
    for (int k0 = 0; k0 < 128; k0 += 32) {
        bf16x8 a = *(const bf16x8*)(hb + arow * HH + k0 + kg * 8);
#pragma unroll
        for (int t = 0; t < 4; t++) {
            bf16x8 b = *(const bf16x8*)&sB1[(t * 16 + ln) * 136 + k0 + kg * 8];
            acc[t] = mfma16(a, b, acc[t]);
        }
    }
#pragma unroll
    for (int t = 0; t < 4; t++) {
        int colt = t * 16 + ln;
        float bb = l1b[colt];
#pragma unroll
        for (int r = 0; r < 4; r++)
            sT[(w * 16 + kg * 4 + r) * 72 + colt] = (bf16)sspf(acc[t][r] + bb);
    }
    __syncthreads();
    f32x4 acc2[4] = {};
#pragma unroll
    for (int k0 = 0; k0 < 64; k0 += 32) {
        bf16x8 a = *(const bf16x8*)&sT[(w * 16 + ln) * 72 + k0 + kg * 8];
#pragma unroll
        for (int t = 0; t < 4; t++) {
            bf16x8 b = *(const bf16x8*)&sB2[(t * 16 + ln) * 72 + k0 + kg * 8];
            acc2[t] = mfma16(a, b, acc2[t]);
        }
    }
#pragma unroll
    for (int t = 0; t < 4; t++) {
        int colt = t * 16 + ln;
        float bb = l2b[colt];
        float v = 0.f;
#pragma unroll
        for (int r = 0; r < 4; r++) {
            int orow = rowt + kg * 4 + r;
            if (orow < NN) v += acc2[t][r] + bb;
        }
        v += __shfl_xor(v, 16);
        v += __shfl_xor(v, 32);
        if (kg == 0) unsafeAtomicAdd(&sumvec[colt], v);
    }
}

__global__ void final_kernel(const float* __restrict__ sumvec, const float* __restrict__ rw,
                             const float* __restrict__ rb, float* __restrict__ out) {
    int j = threadIdx.x;
    if (j >= OUT_DIM) return;
    float s = rb[j];
    for (int i = 0; i < H2D; i++) s += sumvec[i] * rw[i * OUT_DIM + j];
    out[j] = s;
}

// -------- launch -------------------------------------------------------------
extern "C" void kernel_launch(void* const* d_in, const int* in_sizes, int n_in,
                              void* d_out, int out_size, void* d_ws, size_t ws_size,
                              hipStream_t stream) {
    const int*   x_atoms    = (const int*)d_in[0];
    const int*   edge_index = (const int*)d_in[1];
    const float* edge_attr  = (const float*)d_in[2];
    const float* embedding  = (const float*)d_in[3];
    const float* mlp_w1     = (const float*)d_in[4];
    const float* mlp_b1     = (const float*)d_in[5];
    const float* mlp_w2     = (const float*)d_in[6];
    const float* mlp_b2     = (const float*)d_in[7];
    const float* conv1_w    = (const float*)d_in[8];
    const float* conv2_w    = (const float*)d_in[9];
    const float* conv2_b    = (const float*)d_in[10];
    const float* int_lin_w  = (const float*)d_in[11];
    const float* int_lin_b  = (const float*)d_in[12];
    const float* lin1_w     = (const float*)d_in[13];
    const float* lin1_b     = (const float*)d_in[14];
    const float* lin2_w     = (const float*)d_in[15];
    const float* lin2_b     = (const float*)d_in[16];
    const float* readout_w  = (const float*)d_in[17];
    const float* readout_b  = (const float*)d_in[18];

    char* ws = (char*)d_ws;
    float* h      = (float*)(ws + 0);            // 25,600,000 B
    bf16*  hb     = (bf16*)(ws + 25600000);      // 12,800,000 B
    bf16*  xf     = (bf16*)(ws + 38400000);      // 12,800,000 B
    float* agg    = (float*)(ws + 51200000);     // 25,600,000 B
    float* sumvec = (float*)(ws + 76800000);     // 256 B
    size_t wb = 76800256;
    bf16* w1t = (bf16*)(ws + wb);                 // 6*128*64
    bf16* w2t = (bf16*)(ws + wb + 98304);         // 6*128*128
    bf16* c1t = (bf16*)(ws + wb + 294912);
    bf16* c2t = (bf16*)(ws + wb + 491520);
    bf16* ilt = (bf16*)(ws + wb + 688128);
    bf16* l1t = (bf16*)(ws + wb + 884736);        // 64*128
    bf16* l2t = (bf16*)(ws + wb + 901120);        // 64*64

    PrepArgs pa = { mlp_w1, mlp_w2, conv1_w, conv2_w, int_lin_w, lin1_w, lin2_w,
                    w1t, w2t, c1t, c2t, ilt, l1t, l2t };
    prep_kernel<<<32, 256, 0, stream>>>(pa);
    embed_kernel<<<NN * 16 / 256, 256, 0, stream>>>(x_atoms, embedding, h, hb);

    int nblk = (NN + 63) / 64;      // 782
    for (int l = 0; l < LL; l++) {
        hipMemsetAsync(agg, 0, (size_t)NN * FF * 4, stream);
        xf_kernel<<<nblk, 256, 0, stream>>>(hb, c1t + l * FF * HH, xf);
        edge_kernel<<<EE / 64, 256, 0, stream>>>(edge_attr, edge_index, xf,
                                                 w1t + l * FF * 64, w2t + l * FF * FF,
                                                 mlp_b1 + l * FF, mlp_b2 + l * FF, agg);
        update_kernel<<<nblk, 256, 0, stream>>>(agg, c2t + l * HH * FF, conv2_b + l * HH,
                                                ilt + l * HH * HH, int_lin_b + l * HH, h, hb);
    }
    hipMemsetAsync(sumvec, 0, 64 * 4, stream);
    head_kernel<<<nblk, 256, 0, stream>>>(hb, l1t, lin1_b, l2t, lin2_b, sumvec);
    final_kernel<<<1, 64, 0, stream>>>(sumvec, readout_w, readout_b, (float*)d_out);
}

// Round 3
// 3336.257 us; speedup vs baseline: 1.0763x; 1.0763x over previous
//
#include <hip/hip_runtime.h>
#include <hip/hip_bf16.h>
#include <math.h>

#define NN 50000
#define EE 800000
#define HH 128
#define FF 128
#define GG 50
#define LL 6
#define H2D 64
#define OUT_DIM 12

typedef __bf16 bf16;
typedef __attribute__((ext_vector_type(8))) __bf16 bf16x8;
typedef __attribute__((ext_vector_type(4))) float f32x4;

#define DEV __device__ __forceinline__

DEV float sspf(float x) {
    return fmaxf(x, 0.f) + log1pf(__expf(-fabsf(x))) - 0.69314718055994531f;
}

DEV f32x4 mfma16(bf16x8 a, bf16x8 b, f32x4 c) {
    return __builtin_amdgcn_mfma_f32_16x16x32_bf16(a, b, c, 0, 0, 0);
}

// -------- prep: transpose all f32 weights to [n][k] bf16, K zero-padded ------
struct PrepArgs {
    const float *mlp_w1, *mlp_w2, *conv1_w, *conv2_w, *int_lin_w, *lin1_w, *lin2_w;
    bf16 *w1t, *w2t, *c1t, *c2t, *ilt, *l1t, *l2t;
};

__global__ void prep_kernel(PrepArgs p) {
    int j = blockIdx.x;
    const float* src = nullptr; bf16* dst = nullptr; int R = 0, C = 0, K = 0;
    if (j < 30) {
        int l = j / 5, m = j % 5;
        switch (m) {
            case 0: src = p.mlp_w1 + l * GG * FF;  dst = p.w1t + l * FF * 64;  R = GG; C = FF;  K = 64;  break;
            case 1: src = p.mlp_w2 + l * FF * FF;  dst = p.w2t + l * FF * FF;  R = FF; C = FF;  K = FF;  break;
            case 2: src = p.conv1_w + l * HH * FF; dst = p.c1t + l * FF * HH;  R = HH; C = FF;  K = HH;  break;
            case 3: src = p.conv2_w + l * FF * HH; dst = p.c2t + l * HH * FF;  R = FF; C = HH;  K = FF;  break;
            case 4: src = p.int_lin_w + l * HH * HH; dst = p.ilt + l * HH * HH; R = HH; C = HH; K = HH;  break;
        }
    } else if (j == 30) { src = p.lin1_w; dst = p.l1t; R = HH;  C = H2D; K = HH; }
    else               { src = p.lin2_w; dst = p.l2t; R = H2D; C = H2D; K = H2D; }
    int total = C * K;
    for (int idx = threadIdx.x; idx < total; idx += blockDim.x) {
        int c = idx / K, r = idx - c * K;
        dst[idx] = (r < R) ? (bf16)src[r * C + c] : (bf16)0.f;
    }
}

// -------- edge sort by dst: histogram / scan / scatter -----------------------
__global__ void hist_kernel(const int* __restrict__ eidx, int* __restrict__ hist) {
    int e = blockIdx.x * 256 + threadIdx.x;
    if (e < EE) atomicAdd(&hist[eidx[EE + e]], 1);
}

__global__ __launch_bounds__(1024) void scan_kernel(const int* __restrict__ hist,
                                                    int* __restrict__ cur) {
    __shared__ int buf[1024];
    int tid = threadIdx.x;
    const int CH = (NN + 1023) / 1024;          // 49
    int lo = tid * CH, hi = min(lo + CH, NN);
    int s = 0;
    for (int i = lo; i < hi; i++) s += hist[i];
    buf[tid] = s;
    __syncthreads();
    for (int off = 1; off < 1024; off <<= 1) {
        int y = (tid >= off) ? buf[tid - off] : 0;
        __syncthreads();
        buf[tid] += y;
        __syncthreads();
    }
    int run = buf[tid] - s;                     // exclusive prefix for this range
    for (int i = lo; i < hi; i++) { cur[i] = run; run += hist[i]; }
}

__global__ void scatter_kernel(const float* __restrict__ eattr, const int* __restrict__ eidx,
                               int* __restrict__ cur, float* __restrict__ d_sd,
                               int* __restrict__ d_src, int* __restrict__ d_dst) {
    int e = blockIdx.x * 256 + threadIdx.x;
    if (e < EE) {
        int dd = eidx[EE + e];
        int pos = atomicAdd(&cur[dd], 1);
        d_sd[pos] = eattr[e];
        d_src[pos] = eidx[e];
        d_dst[pos] = dd;
    }
}

// -------- embed: h = embedding[x_atoms] (f32 + bf16 copies) ------------------
__global__ void embed_kernel(const int* __restrict__ x_atoms, const float* __restrict__ emb,
                             float* __restrict__ h, bf16* __restrict__ hb) {
    int idx = blockIdx.x * blockDim.x + threadIdx.x;   // over NN*16
    if (idx >= NN * 16) return;
    int n = idx >> 4, ch = idx & 15;
    int a = x_atoms[n];
    const float* ep = emb + a * HH + ch * 8;
    f32x4 v0 = *(const f32x4*)ep;
    f32x4 v1 = *(const f32x4*)(ep + 4);
    float* hp = h + n * HH + ch * 8;
    bf16* hbp = hb + n * HH + ch * 8;
    bf16x8 vb;
#pragma unroll
    for (int q = 0; q < 4; q++) {
        hp[q] = v0[q]; hp[q + 4] = v1[q];
        vb[q] = (bf16)v0[q]; vb[q + 4] = (bf16)v1[q];
    }
    *(bf16x8*)hbp = vb;
}

// -------- xf = h @ conv1_w  (bf16 out) ---------------------------------------
__global__ __launch_bounds__(256) void xf_kernel(const bf16* __restrict__ hb,
                                                 const bf16* __restrict__ c1t,
                                                 bf16* __restrict__ xf) {
    __shared__ bf16 sB[128 * 136];
    int tid = threadIdx.x;
    for (int idx = tid * 8; idx < 128 * 128; idx += 2048) {
        int n = idx >> 7, k = idx & 127;
        *(bf16x8*)&sB[n * 136 + k] = *(const bf16x8*)(c1t + idx);
    }
    int w = tid >> 6, lane = tid & 63, ln = lane & 15, kg = lane >> 4;
    int rowt = blockIdx.x * 64 + w * 16;
    int arow = min(rowt + ln, NN - 1);
    __syncthreads();
    f32x4 acc[8] = {};
#pragma unroll
    for (int k0 = 0; k0 < 128; k0 += 32) {
        bf16x8 a = *(const bf16x8*)(hb + arow * HH + k0 + kg * 8);
#pragma unroll
        for (int t = 0; t < 8; t++) {
            bf16x8 b = *(const bf16x8*)&sB[(t * 16 + ln) * 136 + k0 + kg * 8];
            acc[t] = mfma16(a, b, acc[t]);
        }
    }
#pragma unroll
    for (int t = 0; t < 8; t++) {
        int colt = t * 16 + ln;
#pragma unroll
        for (int r = 0; r < 4; r++) {
            int orow = rowt + kg * 4 + r;
            if (orow < NN) xf[orow * FF + colt] = (bf16)acc[t][r];
        }
    }
}

// -------- fused edge kernel (sorted edges, LDS run reduction) ----------------
__global__ __launch_bounds__(256) void edge_kernel(const float* __restrict__ d_sd,
                                                   const int* __restrict__ d_src,
                                                   const int* __restrict__ d_dst,
                                                   const bf16* __restrict__ xf,
                                                   const bf16* __restrict__ w1t,
                                                   const bf16* __restrict__ w2t,
                                                   const float* __restrict__ b1,
                                                   const float* __restrict__ b2,
                                                   float* __restrict__ agg) {
    __shared__ __align__(16) char smem[70656];
    __shared__ int sDst[64];
    bf16*  sW1  = (bf16*)smem;              // [128][72]  18432 B (aliased: sXf [64][136])
    bf16*  sW2  = (bf16*)(smem + 18432);    // [128][136] 34816 B (aliased: sMsg f32 [64][132])
    bf16*  sT1  = (bf16*)(smem + 53248);    // [64][136]  17408 B
    bf16*  sXf  = sW1;
    float* sMsg = (float*)(smem + 18432);

    int tid = threadIdx.x;
    int eb = blockIdx.x * 64;
    if (tid < 64) sDst[tid] = d_dst[eb + tid];
    for (int idx = tid * 8; idx < 128 * 64; idx += 2048) {
        int n = idx >> 6, k = idx & 63;
        *(bf16x8*)&sW1[n * 72 + k] = *(const bf16x8*)(w1t + idx);
    }
    for (int idx = tid * 8; idx < 128 * 128; idx += 2048) {
        int n = idx >> 7, k = idx & 127;
        *(bf16x8*)&sW2[n * 136 + k] = *(const bf16x8*)(w2t + idx);
    }
    int w = tid >> 6, lane = tid & 63, ln = lane & 15, kg = lane >> 4;
    float d1 = d_sd[eb + w * 16 + ln];
    const float step = 10.f / 49.f;
    const float coeff = -0.5f / (step * step);
    __syncthreads();
    // GEMM1: in-register gaussian expansion @ W1
    f32x4 acc[8] = {};
#pragma unroll
    for (int k0 = 0; k0 < 64; k0 += 32) {
        bf16x8 a;
#pragma unroll
        for (int jj = 0; jj < 8; jj++) {
            int g = k0 + kg * 8 + jj;
            float diff = d1 - g * step;
            float v = (g < GG) ? __expf(coeff * diff * diff) : 0.f;
            a[jj] = (bf16)v;
        }
#pragma unroll
        for (int t = 0; t < 8; t++) {
            bf16x8 b = *(const bf16x8*)&sW1[(t * 16 + ln) * 72 + k0 + kg * 8];
            acc[t] = mfma16(a, b, acc[t]);
        }
    }
    // + b1, ssp, C->A layout via LDS
#pragma unroll
    for (int t = 0; t < 8; t++) {
        int colt = t * 16 + ln;
        float bb = b1[colt];
#pragma unroll
        for (int r = 0; r < 4; r++)
            sT1[(w * 16 + kg * 4 + r) * 136 + colt] = (bf16)sspf(acc[t][r] + bb);
    }
    __syncthreads();   // GEMM1 reads of sW1 done; sT1 visible
    // gather xf[src] rows into sXf (aliases sW1)
    for (int c = tid; c < 64 * 16; c += 256) {
        int row = c >> 4, ch = c & 15;
        int s = d_src[eb + row];
        *(bf16x8*)&sXf[row * 136 + ch * 8] = *(const bf16x8*)(xf + s * FF + ch * 8);
    }
    // GEMM2: t1 @ W2
    f32x4 acc2[8] = {};
#pragma unroll
    for (int k0 = 0; k0 < 128; k0 += 32) {
        bf16x8 a = *(const bf16x8*)&sT1[(w * 16 + ln) * 136 + k0 + kg * 8];
#pragma unroll
        for (int t = 0; t < 8; t++) {
            bf16x8 b = *(const bf16x8*)&sW2[(t * 16 + ln) * 136 + k0 + kg * 8];
            acc2[t] = mfma16(a, b, acc2[t]);
        }
    }
    __syncthreads();   // sXf visible; W2 reads done -> sMsg may overwrite
    // epilogue: msg = (acc2 + b2) * C(d) * xf[src]  -> LDS
    float Cw[4]; int drow[4];
#pragma unroll
    for (int r = 0; r < 4; r++) {
        int lr = w * 16 + kg * 4 + r;
        drow[r] = lr;
        float dd = d_sd[eb + lr];
        Cw[r] = 0.5f * (cosf(dd * 0.31415926535f) + 1.f);
    }
#pragma unroll
    for (int t = 0; t < 8; t++) {
        int colt = t * 16 + ln;
        float b2v = b2[colt];
#pragma unroll
        for (int r = 0; r < 4; r++) {
            float val = (acc2[t][r] + b2v) * Cw[r];
            float xv = (float)sXf[drow[r] * 136 + colt];
            sMsg[drow[r] * 132 + colt] = val * xv;
        }
    }
    __syncthreads();
    // run-length reduce over sorted dst, one coalesced atomic per run
    int col = tid & 127;
    int r0 = (tid >> 7) * 32, r1 = r0 + 32;
    float accv = 0.f;
    for (int r = r0; r < r1; r++) {
        accv += sMsg[r * 132 + col];
        int dcur = sDst[r];
        if (r == r1 - 1 || sDst[r + 1] != dcur) {
            unsafeAtomicAdd(&agg[dcur * FF + col], accv);
            accv = 0.f;
        }
    }
}

// -------- update: h += (ssp(agg@conv2+b) @ int_lin + b) ----------------------
__global__ __launch_bounds__(256) void update_kernel(const float* __restrict__ agg,
                                                     const bf16* __restrict__ c2t,
                                                     const float* __restrict__ c2b,
                                                     const bf16* __restrict__ ilt,
                                                     const float* __restrict__ ilb,
                                                     float* __restrict__ h,
                                                     bf16* __restrict__ hb) {
    __shared__ bf16 sB1[128 * 136];
    __shared__ bf16 sB2[128 * 136];
    __shared__ bf16 sT[64 * 136];
    int tid = threadIdx.x;
    for (int idx = tid * 8; idx < 128 * 128; idx += 2048) {
        int n = idx >> 7, k = idx & 127;
        *(bf16x8*)&sB1[n * 136 + k] = *(const bf16x8*)(c2t + idx);
        *(bf16x8*)&sB2[n * 136 + k] = *(const bf16x8*)(ilt + idx);
    }
    int w = tid >> 6, lane = tid & 63, ln = lane & 15, kg = lane >> 4;
    int rowt = blockIdx.x * 64 + w * 16;
    int arow = min(rowt + ln, NN - 1);
    __syncthreads();
    f32x4 acc[8] = {};
#pragma unroll
    for (int k0 = 0; k0 < 128; k0 += 32) {
        const float* ap = agg + arow * FF + k0 + kg * 8;
        f32x4 u0 = *(const f32x4*)ap;
        f32x4 u1 = *(const f32x4*)(ap + 4);
        bf16x8 a;
#pragma unroll
        for (int q = 0; q < 4; q++) { a[q] = (bf16)u0[q]; a[q + 4] = (bf16)u1[q]; }
#pragma unroll
        for (int t = 0; t < 8; t++) {
            bf16x8 b = *(const bf16x8*)&sB1[(t * 16 + ln) * 136 + k0 + kg * 8];
            acc[t] = mfma16(a, b, acc[t]);
        }
    }
#pragma unroll
    for (int t = 0; t < 8; t++) {
        int colt = t * 16 + ln;
        float bb = c2b[colt];
#pragma unroll
        for (int r = 0; r < 4; r++)
            sT[(w * 16 + kg * 4 + r) * 136 + colt] = (bf16)sspf(acc[t][r] + bb);
    }
    __syncthreads();
    f32x4 acc2[8] = {};
#pragma unroll
    for (int k0 = 0; k0 < 128; k0 += 32) {
        bf16x8 a = *(const bf16x8*)&sT[(w * 16 + ln) * 136 + k0 + kg * 8];
#pragma unroll
        for (int t = 0; t < 8; t++) {
            bf16x8 b = *(const bf16x8*)&sB2[(t * 16 + ln) * 136 + k0 + kg * 8];
            acc2[t] = mfma16(a, b, acc2[t]);
        }
    }
#pragma unroll
    for (int t = 0; t < 8; t++) {
        int colt = t * 16 + ln;
        float bb = ilb[colt];
#pragma unroll
        for (int r = 0; r < 4; r++) {
            int orow = rowt + kg * 4 + r;
            if (orow < NN) {
                float nh = h[orow * HH + colt] + acc2[t][r] + bb;
                h[orow * HH + colt] = nh;
                hb[orow * HH + colt] = (bf16)nh;
            }
        }
    }
}

// -------- head: sum over nodes of (ssp(h@lin1+b)@lin2+b) ---------------------
__global__ __launch_bounds__(256) void head_kernel(const bf16* __restrict__ hb,
                                                   const bf16* __restrict__ l1t,
                                                   const float* __restrict__ l1b,
                                                   const bf16* __restrict__ l2t,
                                                   const float* __restrict__ l2b,
                                                   float* __restrict__ sumvec) {
    __shared__ bf16 sB1[64 * 136];
    __shared__ bf16 sB2[64 * 72];
    __shared__ bf16 sT[64 * 72];
    int tid = threadIdx.x;
    for (int idx = tid * 8; idx < 64 * 128; idx += 2048) {
        int n = idx >> 7, k = idx & 127;
        *(bf16x8*)&sB1[n * 136 + k] = *(const bf16x8*)(l1t + idx);
    }
    for (int idx = tid * 8; idx < 64 * 64; idx += 2048) {
        int n = idx >> 6, k = idx & 63;
        *(bf16x8*)&sB2[n * 72 + k] = *(const bf16x8*)(l2t + idx);
    }
    int w = tid >> 6, lane = tid & 63, ln = lane & 15, kg = lane >> 4;
    int rowt = blockIdx.x * 64 + w * 16;
    int arow = min(rowt + ln, NN - 1);
    __syncthreads();
    f32x4 acc[4] = {};
#pragma unroll
    for (int k0 = 0; k0 < 128; k0 += 32) {
        bf16x8 a = *(const bf16x8*)(hb + arow * HH + k0 + kg * 8);
#pragma unroll
        for (int t = 0; t < 4; t++) {
            bf16x8 b = *(const bf16x8*)&sB1[(t * 16 + ln) * 136 + k0 + kg * 8];
            acc[t] = mfma16(a, b, acc[t]);
        }
    }
#pragma unroll
    for (int t = 0; t < 4; t++) {
        int colt = t * 16 + ln;
        float bb = l1b[colt];
#pragma unroll
        for (int r = 0; r < 4; r++)
            sT[(w * 16 + kg * 4 + r) * 72 + colt] = (bf16)sspf(acc[t][r] + bb);
    }
    __syncthreads();
    f32x4 acc2[4] = {};
#pragma unroll
    for (int k0 = 0; k0 < 64; k0 += 32) {
        bf16x8 a = *(const bf16x8*)&sT[(w * 16 + ln) * 72 + k0 + kg * 8];
#pragma unroll
        for (int t = 0; t < 4; t++) {
            bf16x8 b = *(const bf16x8*)&sB2[(t * 16 + ln) * 72 + k0 + kg * 8];
            acc2[t] = mfma16(a, b, acc2[t]);
        }
    }
#pragma unroll
    for (int t = 0; t < 4; t++) {
        int colt = t * 16 + ln;
        float bb = l2b[colt];
        float v = 0.f;
#pragma unroll
        for (int r = 0; r < 4; r++) {
            int orow = rowt + kg * 4 + r;
            if (orow < NN) v += acc2[t][r] + bb;
        }
        v += __shfl_xor(v, 16);
        v += __shfl_xor(v, 32);
        if (kg == 0) unsafeAtomicAdd(&sumvec[colt], v);
    }
}

__global__ void final_kernel(const float* __restrict__ sumvec, const float* __restrict__ rw,
                             const float* __restrict__ rb, float* __restrict__ out) {
    int j = threadIdx.x;
    if (j >= OUT_DIM) return;
    float s = rb[j];
    for (int i = 0; i < H2D; i++) s += sumvec[i] * rw[i * OUT_DIM + j];
    out[j] = s;
}

// -------- launch -------------------------------------------------------------
extern "C" void kernel_launch(void* const* d_in, const int* in_sizes, int n_in,
                              void* d_out, int out_size, void* d_ws, size_t ws_size,
                              hipStream_t stream) {
    const int*   x_atoms    = (const int*)d_in[0];
    const int*   edge_index = (const int*)d_in[1];
    const float* edge_attr  = (const float*)d_in[2];
    const float* embedding  = (const float*)d_in[3];
    const float* mlp_w1     = (const float*)d_in[4];
    const float* mlp_b1     = (const float*)d_in[5];
    const float* mlp_w2     = (const float*)d_in[6];
    const float* mlp_b2     = (const float*)d_in[7];
    const float* conv1_w    = (const float*)d_in[8];
    const float* conv2_w    = (const float*)d_in[9];
    const float* conv2_b    = (const float*)d_in[10];
    const float* int_lin_w  = (const float*)d_in[11];
    const float* int_lin_b  = (const float*)d_in[12];
    const float* lin1_w     = (const float*)d_in[13];
    const float* lin1_b     = (const float*)d_in[14];
    const float* lin2_w     = (const float*)d_in[15];
    const float* lin2_b     = (const float*)d_in[16];
    const float* readout_w  = (const float*)d_in[17];
    const float* readout_b  = (const float*)d_in[18];

    char* ws = (char*)d_ws;
    float* h      = (float*)(ws + 0);            // 25,600,000 B
    bf16*  hb     = (bf16*)(ws + 25600000);      // 12,800,000 B
    bf16*  xf     = (bf16*)(ws + 38400000);      // 12,800,000 B
    float* agg    = (float*)(ws + 51200000);     // 25,600,000 B
    float* sumvec = (float*)(ws + 76800000);     // 256 B
    size_t wb = 76800256;
    bf16* w1t = (bf16*)(ws + wb);                 // 6*128*64
    bf16* w2t = (bf16*)(ws + wb + 98304);         // 6*128*128
    bf16* c1t = (bf16*)(ws + wb + 294912);
    bf16* c2t = (bf16*)(ws + wb + 491520);
    bf16* ilt = (bf16*)(ws + wb + 688128);
    bf16* l1t = (bf16*)(ws + wb + 884736);        // 64*128
    bf16* l2t = (bf16*)(ws + wb + 901120);        // 64*64
    // sort scratch (after weights, 77,717,760)
    int*   d_hist = (int*)(ws + 77717760);        // 200,000
    int*   d_cur  = (int*)(ws + 77917760);        // 200,000
    float* d_sd   = (float*)(ws + 78117760);      // 3,200,000
    int*   d_src  = (int*)(ws + 81317760);        // 3,200,000
    int*   d_dst  = (int*)(ws + 84517760);        // 3,200,000 -> ends 87,717,760

    PrepArgs pa = { mlp_w1, mlp_w2, conv1_w, conv2_w, int_lin_w, lin1_w, lin2_w,
                    w1t, w2t, c1t, c2t, ilt, l1t, l2t };
    prep_kernel<<<32, 256, 0, stream>>>(pa);
    embed_kernel<<<NN * 16 / 256, 256, 0, stream>>>(x_atoms, embedding, h, hb);

    // sort edges by dst (once; graph static across layers)
    hipMemsetAsync(d_hist, 0, NN * 4, stream);
    hist_kernel<<<(EE + 255) / 256, 256, 0, stream>>>(edge_index, d_hist);
    scan_kernel<<<1, 1024, 0, stream>>>(d_hist, d_cur);
    scatter_kernel<<<(EE + 255) / 256, 256, 0, stream>>>(edge_attr, edge_index, d_cur,
                                                         d_sd, d_src, d_dst);

    int nblk = (NN + 63) / 64;      // 782
    for (int l = 0; l < LL; l++) {
        hipMemsetAsync(agg, 0, (size_t)NN * FF * 4, stream);
        xf_kernel<<<nblk, 256, 0, stream>>>(hb, c1t + l * FF * HH, xf);
        edge_kernel<<<EE / 64, 256, 0, stream>>>(d_sd, d_src, d_dst, xf,
                                                 w1t + l * FF * 64, w2t + l * FF * FF,
                                                 mlp_b1 + l * FF, mlp_b2 + l * FF, agg);
        update_kernel<<<nblk, 256, 0, stream>>>(agg, c2t + l * HH * FF, conv2_b + l * HH,
                                                ilt + l * HH * HH, int_lin_b + l * HH, h, hb);
    }
    hipMemsetAsync(sumvec, 0, 64 * 4, stream);
    head_kernel<<<nblk, 256, 0, stream>>>(hb, l1t, lin1_b, l2t, lin2_b, sumvec);
    final_kernel<<<1, 64, 0, stream>>>(sumvec, readout_w, readout_b, (float*)d_out);
}

// Round 4
// 1446.856 us; speedup vs baseline: 2.4818x; 2.3059x over previous
//
#include <hip/hip_runtime.h>
#include <hip/hip_bf16.h>
#include <math.h>

#define NN 50000
#define EE 800000
#define HH 128
#define FF 128
#define GG 50
#define LL 6
#define H2D 64
#define OUT_DIM 12
#define NK 4096          // table intervals; knots = NK+1, stride 4098 rows/layer

typedef __bf16 bf16;
typedef __attribute__((ext_vector_type(8))) __bf16 bf16x8;
typedef __attribute__((ext_vector_type(4))) float f32x4;

#define DEV __device__ __forceinline__

DEV float sspf(float x) {
    return fmaxf(x, 0.f) + log1pf(__expf(-fabsf(x))) - 0.69314718055994531f;
}

DEV f32x4 mfma16(bf16x8 a, bf16x8 b, f32x4 c) {
    return __builtin_amdgcn_mfma_f32_16x16x32_bf16(a, b, c, 0, 0, 0);
}

DEV float blo(unsigned u) { return __uint_as_float(u << 16); }
DEV float bhi(unsigned u) { return __uint_as_float(u & 0xffff0000u); }

// -------- prep: transpose node-GEMM weights to [n][k] bf16 -------------------
struct PrepArgs {
    const float *conv1_w, *conv2_w, *int_lin_w, *lin1_w, *lin2_w;
    bf16 *c1t, *c2t, *ilt, *l1t, *l2t;
};

__global__ void prep_kernel(PrepArgs p) {
    int j = blockIdx.x;
    const float* src = nullptr; bf16* dst = nullptr; int R = 0, C = 0, K = 0;
    if (j < 18) {
        int l = j / 3, m = j % 3;
        switch (m) {
            case 0: src = p.conv1_w + l * HH * FF;   dst = p.c1t + l * FF * HH;  R = HH; C = FF; K = HH; break;
            case 1: src = p.conv2_w + l * FF * HH;   dst = p.c2t + l * HH * FF;  R = FF; C = HH; K = FF; break;
            case 2: src = p.int_lin_w + l * HH * HH; dst = p.ilt + l * HH * HH;  R = HH; C = HH; K = HH; break;
        }
    } else if (j == 18) { src = p.lin1_w; dst = p.l1t; R = HH;  C = H2D; K = HH; }
    else                { src = p.lin2_w; dst = p.l2t; R = H2D; C = H2D; K = H2D; }
    int total = C * K;
    for (int idx = threadIdx.x; idx < total; idx += blockDim.x) {
        int c = idx / K, r = idx - c * K;
        dst[idx] = (r < R) ? (bf16)src[r * C + c] : (bf16)0.f;
    }
}

// -------- filter table: T[l][r][:] = (ssp(gauss(d)@W1+b1)@W2+b2) * C(d) ------
__global__ __launch_bounds__(128) void table_kernel(const float* __restrict__ mlp_w1,
                                                    const float* __restrict__ mlp_b1,
                                                    const float* __restrict__ mlp_w2,
                                                    const float* __restrict__ mlp_b2,
                                                    bf16* __restrict__ tab) {
    int l = blockIdx.x / (NK + 1);
    int r = blockIdx.x % (NK + 1);
    float d = r * (10.f / NK);
    __shared__ float ed[GG];
    __shared__ float h1[FF];
    int f = threadIdx.x;
    const float step = 10.f / 49.f;
    const float coeff = -0.5f / (step * step);
    if (f < GG) {
        float diff = d - f * step;
        ed[f] = __expf(coeff * diff * diff);
    }
    __syncthreads();
    const float* W1 = mlp_w1 + l * GG * FF;
    float s = mlp_b1[l * FF + f];
    for (int g = 0; g < GG; g++) s += ed[g] * W1[g * FF + f];
    h1[f] = sspf(s);
    __syncthreads();
    const float* W2 = mlp_w2 + l * FF * FF;
    float s2 = mlp_b2[l * FF + f];
    for (int j = 0; j < FF; j++) s2 += h1[j] * W2[j * FF + f];
    float Cw = 0.5f * (cosf(d * 0.31415926535897932f) + 1.f);
    tab[((size_t)l * 4098 + r) * FF + f] = (bf16)(s2 * Cw);
}

// -------- edge sort by dst: histogram / scan / scatter -----------------------
__global__ void hist_kernel(const int* __restrict__ eidx, int* __restrict__ hist) {
    int e = blockIdx.x * 256 + threadIdx.x;
    if (e < EE) atomicAdd(&hist[eidx[EE + e]], 1);
}

__global__ __launch_bounds__(1024) void scan_kernel(const int* __restrict__ hist,
                                                    int* __restrict__ cur) {
    __shared__ int buf[1024];
    int tid = threadIdx.x;
    const int CH = (NN + 1023) / 1024;
    int lo = tid * CH, hi = min(lo + CH, NN);
    int s = 0;
    for (int i = lo; i < hi; i++) s += hist[i];
    buf[tid] = s;
    __syncthreads();
    for (int off = 1; off < 1024; off <<= 1) {
        int y = (tid >= off) ? buf[tid - off] : 0;
        __syncthreads();
        buf[tid] += y;
        __syncthreads();
    }
    int run = buf[tid] - s;
    for (int i = lo; i < hi; i++) { cur[i] = run; run += hist[i]; }
}

__global__ void scatter_kernel(const float* __restrict__ eattr, const int* __restrict__ eidx,
                               int* __restrict__ cur, float* __restrict__ d_sd,
                               int* __restrict__ d_src, int* __restrict__ d_dst) {
    int e = blockIdx.x * 256 + threadIdx.x;
    if (e < EE) {
        int dd = eidx[EE + e];
        int pos = atomicAdd(&cur[dd], 1);
        d_sd[pos] = eattr[e];
        d_src[pos] = eidx[e];
        d_dst[pos] = dd;
    }
}

// -------- embed: h = embedding[x_atoms] (f32) --------------------------------
__global__ void embed_kernel(const int* __restrict__ x_atoms, const float* __restrict__ emb,
                             float* __restrict__ h) {
    int idx = blockIdx.x * blockDim.x + threadIdx.x;   // over NN*16
    if (idx >= NN * 16) return;
    int n = idx >> 4, ch = idx & 15;
    int a = x_atoms[n];
    const float* ep = emb + a * HH + ch * 8;
    f32x4 v0 = *(const f32x4*)ep;
    f32x4 v1 = *(const f32x4*)(ep + 4);
    float* hp = h + n * HH + ch * 8;
    *(f32x4*)hp = v0;
    *(f32x4*)(hp + 4) = v1;
}

// -------- xf = h @ conv1_w  (bf16 out, f32 h in) -----------------------------
__global__ __launch_bounds__(256) void xf_kernel(const float* __restrict__ h,
                                                 const bf16* __restrict__ c1t,
                                                 bf16* __restrict__ xf) {
    __shared__ bf16 sB[128 * 136];
    int tid = threadIdx.x;
    for (int idx = tid * 8; idx < 128 * 128; idx += 2048) {
        int n = idx >> 7, k = idx & 127;
        *(bf16x8*)&sB[n * 136 + k] = *(const bf16x8*)(c1t + idx);
    }
    int w = tid >> 6, lane = tid & 63, ln = lane & 15, kg = lane >> 4;
    int rowt = blockIdx.x * 64 + w * 16;
    int arow = min(rowt + ln, NN - 1);
    __syncthreads();
    f32x4 acc[8] = {};
#pragma unroll
    for (int k0 = 0; k0 < 128; k0 += 32) {
        const float* ap = h + arow * HH + k0 + kg * 8;
        f32x4 u0 = *(const f32x4*)ap;
        f32x4 u1 = *(const f32x4*)(ap + 4);
        bf16x8 a;
#pragma unroll
        for (int q = 0; q < 4; q++) { a[q] = (bf16)u0[q]; a[q + 4] = (bf16)u1[q]; }
#pragma unroll
        for (int t = 0; t < 8; t++) {
            bf16x8 b = *(const bf16x8*)&sB[(t * 16 + ln) * 136 + k0 + kg * 8];
            acc[t] = mfma16(a, b, acc[t]);
        }
    }
#pragma unroll
    for (int t = 0; t < 8; t++) {
        int colt = t * 16 + ln;
#pragma unroll
        for (int r = 0; r < 4; r++) {
            int orow = rowt + kg * 4 + r;
            if (orow < NN) xf[orow * FF + colt] = (bf16)acc[t][r];
        }
    }
}

// -------- edge kernel: table lookup + lerp + gather + run-reduce -------------
__global__ __launch_bounds__(256) void edge_kernel(const float* __restrict__ d_sd,
                                                   const int* __restrict__ d_src,
                                                   const int* __restrict__ d_dst,
                                                   const bf16* __restrict__ xf,
                                                   const bf16* __restrict__ tab,
                                                   float* __restrict__ agg) {
    int tid = threadIdx.x;
    int w = tid >> 6, ln = tid & 63;
    int we = blockIdx.x * 256 + w * 64;     // this wave's 64 sorted edges
    // preload per-lane edge metadata, shuffled per-j later
    float dv = d_sd[we + ln];
    int   sv = d_src[we + ln];
    int   tv = d_dst[we + ln];
    float tt = dv * ((float)NK / 10.f);
    int   kv = (int)tt;
    float fv = tt - (float)kv;

    int run_dst = __shfl(tv, 0);
    float a0 = 0.f, a1 = 0.f;
#pragma unroll 4
    for (int j = 0; j < 64; j++) {
        int dd = __shfl(tv, j);
        if (dd != run_dst) {   // wave-uniform branch
            unsafeAtomicAdd(&agg[run_dst * FF + 2 * ln],     a0);
            unsafeAtomicAdd(&agg[run_dst * FF + 2 * ln + 1], a1);
            a0 = 0.f; a1 = 0.f; run_dst = dd;
        }
        int   k  = __shfl(kv, j);
        float fr = __shfl(fv, j);
        int   s  = __shfl(sv, j);
        unsigned t0 = *(const unsigned*)(tab + k * FF + 2 * ln);
        unsigned t1 = *(const unsigned*)(tab + (k + 1) * FF + 2 * ln);
        unsigned xu = *(const unsigned*)(xf + s * FF + 2 * ln);
        float w00 = blo(t0), w01 = bhi(t0);
        float w10 = blo(t1), w11 = bhi(t1);
        float wa = fmaf(fr, w10 - w00, w00);
        float wb = fmaf(fr, w11 - w01, w01);
        a0 = fmaf(wa, blo(xu), a0);
        a1 = fmaf(wb, bhi(xu), a1);
    }
    unsafeAtomicAdd(&agg[run_dst * FF + 2 * ln],     a0);
    unsafeAtomicAdd(&agg[run_dst * FF + 2 * ln + 1], a1);
}

// -------- update: h += (ssp(agg@conv2+b) @ int_lin + b) ----------------------
__global__ __launch_bounds__(256) void update_kernel(const float* __restrict__ agg,
                                                     const bf16* __restrict__ c2t,
                                                     const float* __restrict__ c2b,
                                                     const bf16* __restrict__ ilt,
                                                     const float* __restrict__ ilb,
                                                     float* __restrict__ h) {
    __shared__ bf16 sB1[128 * 136];
    __shared__ bf16 sB2[128 * 136];
    __shared__ bf16 sT[64 * 136];
    int tid = threadIdx.x;
    for (int idx = tid * 8; idx < 128 * 128; idx += 2048) {
        int n = idx >> 7, k = idx & 127;
        *(bf16x8*)&sB1[n * 136 + k] = *(const bf16x8*)(c2t + idx);
        *(bf16x8*)&sB2[n * 136 + k] = *(const bf16x8*)(ilt + idx);
    }
    int w = tid >> 6, lane = tid & 63, ln = lane & 15, kg = lane >> 4;
    int rowt = blockIdx.x * 64 + w * 16;
    int arow = min(rowt + ln, NN - 1);
    __syncthreads();
    f32x4 acc[8] = {};
#pragma unroll
    for (int k0 = 0; k0 < 128; k0 += 32) {
        const float* ap = agg + arow * FF + k0 + kg * 8;
        f32x4 u0 = *(const f32x4*)ap;
        f32x4 u1 = *(const f32x4*)(ap + 4);
        bf16x8 a;
#pragma unroll
        for (int q = 0; q < 4; q++) { a[q] = (bf16)u0[q]; a[q + 4] = (bf16)u1[q]; }
#pragma unroll
        for (int t = 0; t < 8; t++) {
            bf16x8 b = *(const bf16x8*)&sB1[(t * 16 + ln) * 136 + k0 + kg * 8];
            acc[t] = mfma16(a, b, acc[t]);
        }
    }
#pragma unroll
    for (int t = 0; t < 8; t++) {
        int colt = t * 16 + ln;
        float bb = c2b[colt];
#pragma unroll
        for (int r = 0; r < 4; r++)
            sT[(w * 16 + kg * 4 + r) * 136 + colt] = (bf16)sspf(acc[t][r] + bb);
    }
    __syncthreads();
    f32x4 acc2[8] = {};
#pragma unroll
    for (int k0 = 0; k0 < 128; k0 += 32) {
        bf16x8 a = *(const bf16x8*)&sT[(w * 16 + ln) * 136 + k0 + kg * 8];
#pragma unroll
        for (int t = 0; t < 8; t++) {
            bf16x8 b = *(const bf16x8*)&sB2[(t * 16 + ln) * 136 + k0 + kg * 8];
            acc2[t] = mfma16(a, b, acc2[t]);
        }
    }
#pragma unroll
    for (int t = 0; t < 8; t++) {
        int colt = t * 16 + ln;
        float bb = ilb[colt];
#pragma unroll
        for (int r = 0; r < 4; r++) {
            int orow = rowt + kg * 4 + r;
            if (orow < NN)
                h[orow * HH + colt] += acc2[t][r] + bb;
        }
    }
}

// -------- head: sum over nodes of (ssp(h@lin1+b)@lin2+b) ---------------------
__global__ __launch_bounds__(256) void head_kernel(const float* __restrict__ h,
                                                   const bf16* __restrict__ l1t,
                                                   const float* __restrict__ l1b,
                                                   const bf16* __restrict__ l2t,
                                                   const float* __restrict__ l2b,
                                                   float* __restrict__ sumvec) {
    __shared__ bf16 sB1[64 * 136];
    __shared__ bf16 sB2[64 * 72];
    __shared__ bf16 sT[64 * 72];
    int tid = threadIdx.x;
    for (int idx = tid * 8; idx < 64 * 128; idx += 2048) {
        int n = idx >> 7, k = idx & 127;
        *(bf16x8*)&sB1[n * 136 + k] = *(const bf16x8*)(l1t + idx);
    }
    for (int idx = tid * 8; idx < 64 * 64; idx += 2048) {
        int n = idx >> 6, k = idx & 63;
        *(bf16x8*)&sB2[n * 72 + k] = *(const bf16x8*)(l2t + idx);
    }
    int w = tid >> 6, lane = tid & 63, ln = lane & 15, kg = lane >> 4;
    int rowt = blockIdx.x * 64 + w * 16;
    int arow = min(rowt + ln, NN - 1);
    __syncthreads();
    f32x4 acc[4] = {};
#pragma unroll
    for (int k0 = 0; k0 < 128; k0 += 32) {
        const float* ap = h + arow * HH + k0 + kg * 8;
        f32x4 u0 = *(const f32x4*)ap;
        f32x4 u1 = *(const f32x4*)(ap + 4);
        bf16x8 a;
#pragma unroll
        for (int q = 0; q < 4; q++) { a[q] = (bf16)u0[q]; a[q + 4] = (bf16)u1[q]; }
#pragma unroll
        for (int t = 0; t < 4; t++) {
            bf16x8 b = *(const bf16x8*)&sB1[(t * 16 + ln) * 136 + k0 + kg * 8];
            acc[t] = mfma16(a, b, acc[t]);
        }
    }
#pragma unroll
    for (int t = 0; t < 4; t++) {
        int colt = t * 16 + ln;
        float bb = l1b[colt];
#pragma unroll
        for (int r = 0; r < 4; r++)
            sT[(w * 16 + kg * 4 + r) * 72 + colt] = (bf16)sspf(acc[t][r] + bb);
    }
    __syncthreads();
    f32x4 acc2[4] = {};
#pragma unroll
    for (int k0 = 0; k0 < 64; k0 += 32) {
        bf16x8 a = *(const bf16x8*)&sT[(w * 16 + ln) * 72 + k0 + kg * 8];
#pragma unroll
        for (int t = 0; t < 4; t++) {
            bf16x8 b = *(const bf16x8*)&sB2[(t * 16 + ln) * 72 + k0 + kg * 8];
            acc2[t] = mfma16(a, b, acc2[t]);
        }
    }
#pragma unroll
    for (int t = 0; t < 4; t++) {
        int colt = t * 16 + ln;
        float bb = l2b[colt];
        float v = 0.f;
#pragma unroll
        for (int r = 0; r < 4; r++) {
            int orow = rowt + kg * 4 + r;
            if (orow < NN) v += acc2[t][r] + bb;
        }
        v += __shfl_xor(v, 16);
        v += __shfl_xor(v, 32);
        if (kg == 0) unsafeAtomicAdd(&sumvec[colt], v);
    }
}

__global__ void final_kernel(const float* __restrict__ sumvec, const float* __restrict__ rw,
                             const float* __restrict__ rb, float* __restrict__ out) {
    int j = threadIdx.x;
    if (j >= OUT_DIM) return;
    float s = rb[j];
    for (int i = 0; i < H2D; i++) s += sumvec[i] * rw[i * OUT_DIM + j];
    out[j] = s;
}

// -------- launch -------------------------------------------------------------
extern "C" void kernel_launch(void* const* d_in, const int* in_sizes, int n_in,
                              void* d_out, int out_size, void* d_ws, size_t ws_size,
                              hipStream_t stream) {
    const int*   x_atoms    = (const int*)d_in[0];
    const int*   edge_index = (const int*)d_in[1];
    const float* edge_attr  = (const float*)d_in[2];
    const float* embedding  = (const float*)d_in[3];
    const float* mlp_w1     = (const float*)d_in[4];
    const float* mlp_b1     = (const float*)d_in[5];
    const float* mlp_w2     = (const float*)d_in[6];
    const float* mlp_b2     = (const float*)d_in[7];
    const float* conv1_w    = (const float*)d_in[8];
    const float* conv2_w    = (const float*)d_in[9];
    const float* conv2_b    = (const float*)d_in[10];
    const float* int_lin_w  = (const float*)d_in[11];
    const float* int_lin_b  = (const float*)d_in[12];
    const float* lin1_w     = (const float*)d_in[13];
    const float* lin1_b     = (const float*)d_in[14];
    const float* lin2_w     = (const float*)d_in[15];
    const float* lin2_b     = (const float*)d_in[16];
    const float* readout_w  = (const float*)d_in[17];
    const float* readout_b  = (const float*)d_in[18];

    char* ws = (char*)d_ws;
    float* h      = (float*)(ws + 0);             // 25,600,000
    bf16*  xf     = (bf16*)(ws + 25600000);       // 12,800,000
    float* agg    = (float*)(ws + 38400000);      // 25,600,000
    float* sumvec = (float*)(ws + 64000000);      // 256
    size_t wb = 64000256;
    bf16* c1t = (bf16*)(ws + wb);                 // 196,608
    bf16* c2t = (bf16*)(ws + wb + 196608);
    bf16* ilt = (bf16*)(ws + wb + 393216);
    bf16* l1t = (bf16*)(ws + wb + 589824);        // 16,384
    bf16* l2t = (bf16*)(ws + wb + 606208);        // 8,192
    // sort scratch
    int*   d_hist = (int*)(ws + 64614656);        // 200,000
    int*   d_cur  = (int*)(ws + 64814656);        // 200,000
    float* d_sd   = (float*)(ws + 65014656);      // 3,200,000
    int*   d_src  = (int*)(ws + 68214656);        // 3,200,000
    int*   d_dst  = (int*)(ws + 71414656);        // 3,200,000
    // filter tables: [L][4098][128] bf16 = 6,294,528
    bf16*  tab    = (bf16*)(ws + 74614656);       // ends 80,909,184

    PrepArgs pa = { conv1_w, conv2_w, int_lin_w, lin1_w, lin2_w,
                    c1t, c2t, ilt, l1t, l2t };
    prep_kernel<<<20, 256, 0, stream>>>(pa);
    table_kernel<<<LL * (NK + 1), 128, 0, stream>>>(mlp_w1, mlp_b1, mlp_w2, mlp_b2, tab);
    embed_kernel<<<NN * 16 / 256, 256, 0, stream>>>(x_atoms, embedding, h);

    // sort edges by dst (once; graph static across layers)
    hipMemsetAsync(d_hist, 0, NN * 4, stream);
    hist_kernel<<<(EE + 255) / 256, 256, 0, stream>>>(edge_index, d_hist);
    scan_kernel<<<1, 1024, 0, stream>>>(d_hist, d_cur);
    scatter_kernel<<<(EE + 255) / 256, 256, 0, stream>>>(edge_attr, edge_index, d_cur,
                                                         d_sd, d_src, d_dst);

    int nblk = (NN + 63) / 64;      // 782
    for (int l = 0; l < LL; l++) {
        hipMemsetAsync(agg, 0, (size_t)NN * FF * 4, stream);
        xf_kernel<<<nblk, 256, 0, stream>>>(h, c1t + l * FF * HH, xf);
        edge_kernel<<<EE / 256, 256, 0, stream>>>(d_sd, d_src, d_dst, xf,
                                                  tab + (size_t)l * 4098 * FF, agg);
        update_kernel<<<nblk, 256, 0, stream>>>(agg, c2t + l * HH * FF, conv2_b + l * HH,
                                                ilt + l * HH * HH, int_lin_b + l * HH, h);
    }
    hipMemsetAsync(sumvec, 0, 64 * 4, stream);
    head_kernel<<<nblk, 256, 0, stream>>>(h, l1t, lin1_b, l2t, lin2_b, sumvec);
    final_kernel<<<1, 64, 0, stream>>>(sumvec, readout_w, readout_b, (float*)d_out);
}

// Round 5
// 1120.504 us; speedup vs baseline: 3.2046x; 1.2913x over previous
//
#include <hip/hip_runtime.h>
#include <hip/hip_bf16.h>
#include <math.h>

#define NN 50000
#define EE 800000
#define HH 128
#define FF 128
#define GG 50
#define LL 6
#define H2D 64
#define OUT_DIM 12
#define NK 4096          // table intervals; knots = NK+1, stride 4098 rows/layer
#define NBLK 782         // ceil(NN/64)

typedef __bf16 bf16;
typedef __attribute__((ext_vector_type(8))) __bf16 bf16x8;
typedef __attribute__((ext_vector_type(4))) float f32x4;
typedef __attribute__((ext_vector_type(2))) float f32x2;

#define DEV __device__ __forceinline__

DEV float sspf(float x) {
    return fmaxf(x, 0.f) + log1pf(__expf(-fabsf(x))) - 0.69314718055994531f;
}

DEV f32x4 mfma16(bf16x8 a, bf16x8 b, f32x4 c) {
    return __builtin_amdgcn_mfma_f32_16x16x32_bf16(a, b, c, 0, 0, 0);
}

DEV float blo(unsigned u) { return __uint_as_float(u << 16); }
DEV float bhi(unsigned u) { return __uint_as_float(u & 0xffff0000u); }

// -------- prep: transpose node-GEMM weights to [n][k] bf16 -------------------
struct PrepArgs {
    const float *conv1_w, *conv2_w, *int_lin_w, *lin1_w, *lin2_w;
    bf16 *c1t, *c2t, *ilt, *l1t, *l2t;
};

__global__ void prep_kernel(PrepArgs p) {
    int j = blockIdx.x;
    const float* src = nullptr; bf16* dst = nullptr; int R = 0, C = 0, K = 0;
    if (j < 18) {
        int l = j / 3, m = j % 3;
        switch (m) {
            case 0: src = p.conv1_w + l * HH * FF;   dst = p.c1t + l * FF * HH;  R = HH; C = FF; K = HH; break;
            case 1: src = p.conv2_w + l * FF * HH;   dst = p.c2t + l * HH * FF;  R = FF; C = HH; K = FF; break;
            case 2: src = p.int_lin_w + l * HH * HH; dst = p.ilt + l * HH * HH;  R = HH; C = HH; K = HH; break;
        }
    } else if (j == 18) { src = p.lin1_w; dst = p.l1t; R = HH;  C = H2D; K = HH; }
    else                { src = p.lin2_w; dst = p.l2t; R = H2D; C = H2D; K = H2D; }
    int total = C * K;
    for (int idx = threadIdx.x; idx < total; idx += blockDim.x) {
        int c = idx / K, r = idx - c * K;
        dst[idx] = (r < R) ? (bf16)src[r * C + c] : (bf16)0.f;
    }
}

// -------- filter table: T[l][r][:] = (ssp(gauss(d)@W1+b1)@W2+b2) * C(d) ------
__global__ __launch_bounds__(128) void table_kernel(const float* __restrict__ mlp_w1,
                                                    const float* __restrict__ mlp_b1,
                                                    const float* __restrict__ mlp_w2,
                                                    const float* __restrict__ mlp_b2,
                                                    bf16* __restrict__ tab) {
    int l = blockIdx.x / (NK + 1);
    int r = blockIdx.x % (NK + 1);
    float d = r * (10.f / NK);
    __shared__ float ed[GG];
    __shared__ float h1[FF];
    int f = threadIdx.x;
    const float step = 10.f / 49.f;
    const float coeff = -0.5f / (step * step);
    if (f < GG) {
        float diff = d - f * step;
        ed[f] = __expf(coeff * diff * diff);
    }
    __syncthreads();
    const float* W1 = mlp_w1 + l * GG * FF;
    float s = mlp_b1[l * FF + f];
    for (int g = 0; g < GG; g++) s += ed[g] * W1[g * FF + f];
    h1[f] = sspf(s);
    __syncthreads();
    const float* W2 = mlp_w2 + l * FF * FF;
    float s2 = mlp_b2[l * FF + f];
    for (int j = 0; j < FF; j++) s2 += h1[j] * W2[j * FF + f];
    float Cw = 0.5f * (cosf(d * 0.31415926535897932f) + 1.f);
    tab[((size_t)l * 4098 + r) * FF + f] = (bf16)(s2 * Cw);
}

// -------- edge sort by dst: histogram / scan / scatter -----------------------
__global__ void hist_kernel(const int* __restrict__ eidx, int* __restrict__ hist) {
    int e = blockIdx.x * 256 + threadIdx.x;
    if (e < EE) atomicAdd(&hist[eidx[EE + e]], 1);
}

__global__ __launch_bounds__(1024) void scan_kernel(const int* __restrict__ hist,
                                                    int* __restrict__ rs,
                                                    int* __restrict__ cur) {
    __shared__ int buf[1024];
    int tid = threadIdx.x;
    const int CH = (NN + 1023) / 1024;
    int lo = tid * CH, hi = min(lo + CH, NN);
    int s = 0;
    for (int i = lo; i < hi; i++) s += hist[i];
    buf[tid] = s;
    __syncthreads();
    for (int off = 1; off < 1024; off <<= 1) {
        int y = (tid >= off) ? buf[tid - off] : 0;
        __syncthreads();
        buf[tid] += y;
        __syncthreads();
    }
    int run = buf[tid] - s;
    for (int i = lo; i < hi; i++) { rs[i] = run; cur[i] = run; run += hist[i]; }
}

__global__ void scatter_kernel(const float* __restrict__ eattr, const int* __restrict__ eidx,
                               int* __restrict__ cur, float* __restrict__ d_sd,
                               int* __restrict__ d_src) {
    int e = blockIdx.x * 256 + threadIdx.x;
    if (e < EE) {
        int dd = eidx[EE + e];
        int pos = atomicAdd(&cur[dd], 1);
        d_sd[pos] = eattr[e];
        d_src[pos] = eidx[e];
    }
}

// -------- embed: h = embedding[x_atoms] (f32) --------------------------------
__global__ void embed_kernel(const int* __restrict__ x_atoms, const float* __restrict__ emb,
                             float* __restrict__ h) {
    int idx = blockIdx.x * blockDim.x + threadIdx.x;   // over NN*16
    if (idx >= NN * 16) return;
    int n = idx >> 4, ch = idx & 15;
    int a = x_atoms[n];
    const float* ep = emb + a * HH + ch * 8;
    f32x4 v0 = *(const f32x4*)ep;
    f32x4 v1 = *(const f32x4*)(ep + 4);
    float* hp = h + n * HH + ch * 8;
    *(f32x4*)hp = v0;
    *(f32x4*)(hp + 4) = v1;
}

// -------- xf = h @ conv1_w  (bf16 out, f32 h in) -----------------------------
__global__ __launch_bounds__(256) void xf_kernel(const float* __restrict__ h,
                                                 const bf16* __restrict__ c1t,
                                                 bf16* __restrict__ xf) {
    __shared__ bf16 sB[128 * 136];
    int tid = threadIdx.x;
    for (int idx = tid * 8; idx < 128 * 128; idx += 2048) {
        int n = idx >> 7, k = idx & 127;
        *(bf16x8*)&sB[n * 136 + k] = *(const bf16x8*)(c1t + idx);
    }
    int w = tid >> 6, lane = tid & 63, ln = lane & 15, kg = lane >> 4;
    int rowt = blockIdx.x * 64 + w * 16;
    int arow = min(rowt + ln, NN - 1);
    __syncthreads();
    f32x4 acc[8] = {};
#pragma unroll
    for (int k0 = 0; k0 < 128; k0 += 32) {
        const float* ap = h + arow * HH + k0 + kg * 8;
        f32x4 u0 = *(const f32x4*)ap;
        f32x4 u1 = *(const f32x4*)(ap + 4);
        bf16x8 a;
#pragma unroll
        for (int q = 0; q < 4; q++) { a[q] = (bf16)u0[q]; a[q + 4] = (bf16)u1[q]; }
#pragma unroll
        for (int t = 0; t < 8; t++) {
            bf16x8 b = *(const bf16x8*)&sB[(t * 16 + ln) * 136 + k0 + kg * 8];
            acc[t] = mfma16(a, b, acc[t]);
        }
    }
#pragma unroll
    for (int t = 0; t < 8; t++) {
        int colt = t * 16 + ln;
#pragma unroll
        for (int r = 0; r < 4; r++) {
            int orow = rowt + kg * 4 + r;
            if (orow < NN) xf[orow * FF + colt] = (bf16)acc[t][r];
        }
    }
}

// -------- edge kernel: CSR, one wave per node, no atomics --------------------
__global__ __launch_bounds__(256) void edge_kernel(const float* __restrict__ d_sd,
                                                   const int* __restrict__ d_src,
                                                   const int* __restrict__ d_rs,
                                                   const int* __restrict__ d_hist,
                                                   const bf16* __restrict__ xf,
                                                   const bf16* __restrict__ tab,
                                                   float* __restrict__ agg) {
    int tid = threadIdx.x;
    int w = tid >> 6, ln = tid & 63;
    int n = blockIdx.x * 4 + w;
    int start = d_rs[n], deg = d_hist[n];
    float a0 = 0.f, a1 = 0.f;
    for (int base = 0; base < deg; base += 64) {
        int cnt = min(deg - base, 64);
        float dv = 0.f; int sv = 0;
        if (ln < cnt) {
            dv = d_sd[start + base + ln];
            sv = d_src[start + base + ln];
        }
        float tt = dv * ((float)NK / 10.f);
        int   kv = (int)tt;
        float fv = tt - (float)kv;
#pragma unroll 2
        for (int j = 0; j < cnt; j++) {
            int   k  = __shfl(kv, j);
            float fr = __shfl(fv, j);
            int   s  = __shfl(sv, j);
            unsigned t0 = *(const unsigned*)(tab + k * FF + 2 * ln);
            unsigned t1 = *(const unsigned*)(tab + (k + 1) * FF + 2 * ln);
            unsigned xu = *(const unsigned*)(xf + s * FF + 2 * ln);
            float wa = fmaf(fr, blo(t1) - blo(t0), blo(t0));
            float wb = fmaf(fr, bhi(t1) - bhi(t0), bhi(t0));
            a0 = fmaf(wa, blo(xu), a0);
            a1 = fmaf(wb, bhi(xu), a1);
        }
    }
    f32x2 o; o[0] = a0; o[1] = a1;
    *(f32x2*)(agg + n * FF + 2 * ln) = o;
}

// -------- update: h += (ssp(agg@conv2+b) @ int_lin + b) ----------------------
// single weight-staging buffer used sequentially -> 52 KB LDS, 3 blocks/CU
__global__ __launch_bounds__(256) void update_kernel(const float* __restrict__ agg,
                                                     const bf16* __restrict__ c2t,
                                                     const float* __restrict__ c2b,
                                                     const bf16* __restrict__ ilt,
                                                     const float* __restrict__ ilb,
                                                     float* __restrict__ h) {
    __shared__ bf16 sB[128 * 136];
    __shared__ bf16 sT[64 * 136];
    int tid = threadIdx.x;
    for (int idx = tid * 8; idx < 128 * 128; idx += 2048) {
        int n = idx >> 7, k = idx & 127;
        *(bf16x8*)&sB[n * 136 + k] = *(const bf16x8*)(c2t + idx);
    }
    int w = tid >> 6, lane = tid & 63, ln = lane & 15, kg = lane >> 4;
    int rowt = blockIdx.x * 64 + w * 16;
    int arow = min(rowt + ln, NN - 1);
    __syncthreads();
    f32x4 acc[8] = {};
#pragma unroll
    for (int k0 = 0; k0 < 128; k0 += 32) {
        const float* ap = agg + arow * FF + k0 + kg * 8;
        f32x4 u0 = *(const f32x4*)ap;
        f32x4 u1 = *(const f32x4*)(ap + 4);
        bf16x8 a;
#pragma unroll
        for (int q = 0; q < 4; q++) { a[q] = (bf16)u0[q]; a[q + 4] = (bf16)u1[q]; }
#pragma unroll
        for (int t = 0; t < 8; t++) {
            bf16x8 b = *(const bf16x8*)&sB[(t * 16 + ln) * 136 + k0 + kg * 8];
            acc[t] = mfma16(a, b, acc[t]);
        }
    }
#pragma unroll
    for (int t = 0; t < 8; t++) {
        int colt = t * 16 + ln;
        float bb = c2b[colt];
#pragma unroll
        for (int r = 0; r < 4; r++)
            sT[(w * 16 + kg * 4 + r) * 136 + colt] = (bf16)sspf(acc[t][r] + bb);
    }
    __syncthreads();   // all GEMM1 reads of sB done, sT visible
    // restage sB with int_lin weights
    for (int idx = tid * 8; idx < 128 * 128; idx += 2048) {
        int n = idx >> 7, k = idx & 127;
        *(bf16x8*)&sB[n * 136 + k] = *(const bf16x8*)(ilt + idx);
    }
    __syncthreads();
    f32x4 acc2[8] = {};
#pragma unroll
    for (int k0 = 0; k0 < 128; k0 += 32) {
        bf16x8 a = *(const bf16x8*)&sT[(w * 16 + ln) * 136 + k0 + kg * 8];
#pragma unroll
        for (int t = 0; t < 8; t++) {
            bf16x8 b = *(const bf16x8*)&sB[(t * 16 + ln) * 136 + k0 + kg * 8];
            acc2[t] = mfma16(a, b, acc2[t]);
        }
    }
#pragma unroll
    for (int t = 0; t < 8; t++) {
        int colt = t * 16 + ln;
        float bb = ilb[colt];
#pragma unroll
        for (int r = 0; r < 4; r++) {
            int orow = rowt + kg * 4 + r;
            if (orow < NN)
                h[orow * HH + colt] += acc2[t][r] + bb;
        }
    }
}

// -------- head: per-block partial sums of (ssp(h@lin1+b)@lin2+b) -------------
__global__ __launch_bounds__(256) void head_kernel(const float* __restrict__ h,
                                                   const bf16* __restrict__ l1t,
                                                   const float* __restrict__ l1b,
                                                   const bf16* __restrict__ l2t,
                                                   const float* __restrict__ l2b,
                                                   float* __restrict__ partial) {
    __shared__ bf16 sB1[64 * 136];
    __shared__ bf16 sB2[64 * 72];
    __shared__ bf16 sT[64 * 72];
    float* sPart = (float*)sT;            // reused after barrier: [4][64] f32
    int tid = threadIdx.x;
    for (int idx = tid * 8; idx < 64 * 128; idx += 2048) {
        int n = idx >> 7, k = idx & 127;
        *(bf16x8*)&sB1[n * 136 + k] = *(const bf16x8*)(l1t + idx);
    }
    for (int idx = tid * 8; idx < 64 * 64; idx += 2048) {
        int n = idx >> 6, k = idx & 63;
        *(bf16x8*)&sB2[n * 72 + k] = *(const bf16x8*)(l2t + idx);
    }
    int w = tid >> 6, lane = tid & 63, ln = lane & 15, kg = lane >> 4;
    int rowt = blockIdx.x * 64 + w * 16;
    int arow = min(rowt + ln, NN - 1);
    __syncthreads();
    f32x4 acc[4] = {};
#pragma unroll
    for (int k0 = 0; k0 < 128; k0 += 32) {
        const float* ap = h + arow * HH + k0 + kg * 8;
        f32x4 u0 = *(const f32x4*)ap;
        f32x4 u1 = *(const f32x4*)(ap + 4);
        bf16x8 a;
#pragma unroll
        for (int q = 0; q < 4; q++) { a[q] = (bf16)u0[q]; a[q + 4] = (bf16)u1[q]; }
#pragma unroll
        for (int t = 0; t < 4; t++) {
            bf16x8 b = *(const bf16x8*)&sB1[(t * 16 + ln) * 136 + k0 + kg * 8];
            acc[t] = mfma16(a, b, acc[t]);
        }
    }
#pragma unroll
    for (int t = 0; t < 4; t++) {
        int colt = t * 16 + ln;
        float bb = l1b[colt];
#pragma unroll
        for (int r = 0; r < 4; r++)
            sT[(w * 16 + kg * 4 + r) * 72 + colt] = (bf16)sspf(acc[t][r] + bb);
    }
    __syncthreads();
    f32x4 acc2[4] = {};
#pragma unroll
    for (int k0 = 0; k0 < 64; k0 += 32) {
        bf16x8 a = *(const bf16x8*)&sT[(w * 16 + ln) * 72 + k0 + kg * 8];
#pragma unroll
        for (int t = 0; t < 4; t++) {
            bf16x8 b = *(const bf16x8*)&sB2[(t * 16 + ln) * 72 + k0 + kg * 8];
            acc2[t] = mfma16(a, b, acc2[t]);
        }
    }
    __syncthreads();   // all GEMM2 reads of sT done; safe to reuse as sPart
#pragma unroll
    for (int t = 0; t < 4; t++) {
        int colt = t * 16 + ln;
        float bb = l2b[colt];
        float v = 0.f;
#pragma unroll
        for (int r = 0; r < 4; r++) {
            int orow = rowt + kg * 4 + r;
            if (orow < NN) v += acc2[t][r] + bb;
        }
        v += __shfl_xor(v, 16);
        v += __shfl_xor(v, 32);
        if (kg == 0) sPart[w * 64 + colt] = v;
    }
    __syncthreads();
    if (tid < 64) {
        float s = sPart[tid] + sPart[64 + tid] + sPart[128 + tid] + sPart[192 + tid];
        partial[blockIdx.x * 64 + tid] = s;
    }
}

__global__ __launch_bounds__(64) void final_kernel(const float* __restrict__ partial,
                                                   const float* __restrict__ rw,
                                                   const float* __restrict__ rb,
                                                   float* __restrict__ out) {
    __shared__ float sv[64];
    int j = threadIdx.x;
    float s = 0.f;
    for (int b = 0; b < NBLK; b++) s += partial[b * 64 + j];
    sv[j] = s;
    __syncthreads();
    if (j < OUT_DIM) {
        float o = rb[j];
        for (int i = 0; i < H2D; i++) o += sv[i] * rw[i * OUT_DIM + j];
        out[j] = o;
    }
}

// -------- launch -------------------------------------------------------------
extern "C" void kernel_launch(void* const* d_in, const int* in_sizes, int n_in,
                              void* d_out, int out_size, void* d_ws, size_t ws_size,
                              hipStream_t stream) {
    const int*   x_atoms    = (const int*)d_in[0];
    const int*   edge_index = (const int*)d_in[1];
    const float* edge_attr  = (const float*)d_in[2];
    const float* embedding  = (const float*)d_in[3];
    const float* mlp_w1     = (const float*)d_in[4];
    const float* mlp_b1     = (const float*)d_in[5];
    const float* mlp_w2     = (const float*)d_in[6];
    const float* mlp_b2     = (const float*)d_in[7];
    const float* conv1_w    = (const float*)d_in[8];
    const float* conv2_w    = (const float*)d_in[9];
    const float* conv2_b    = (const float*)d_in[10];
    const float* int_lin_w  = (const float*)d_in[11];
    const float* int_lin_b  = (const float*)d_in[12];
    const float* lin1_w     = (const float*)d_in[13];
    const float* lin1_b     = (const float*)d_in[14];
    const float* lin2_w     = (const float*)d_in[15];
    const float* lin2_b     = (const float*)d_in[16];
    const float* readout_w  = (const float*)d_in[17];
    const float* readout_b  = (const float*)d_in[18];

    char* ws = (char*)d_ws;
    float* h       = (float*)(ws + 0);             // 25,600,000
    bf16*  xf      = (bf16*)(ws + 25600000);       // 12,800,000
    float* agg     = (float*)(ws + 38400000);      // 25,600,000
    float* partial = (float*)(ws + 64000000);      // 200,192 (782*64*4)
    size_t wb = 64200192;
    bf16* c1t = (bf16*)(ws + wb);                  // 196,608
    bf16* c2t = (bf16*)(ws + wb + 196608);
    bf16* ilt = (bf16*)(ws + wb + 393216);
    bf16* l1t = (bf16*)(ws + wb + 589824);         // 16,384
    bf16* l2t = (bf16*)(ws + wb + 606208);         // 8,192
    // sort scratch (from 64,814,592)
    int*   d_hist = (int*)(ws + 64814592);         // 200,000
    int*   d_rs   = (int*)(ws + 65014592);         // 200,000
    int*   d_cur  = (int*)(ws + 65214592);         // 200,000
    float* d_sd   = (float*)(ws + 65414592);       // 3,200,000
    int*   d_src  = (int*)(ws + 68614592);         // 3,200,000
    // filter tables: [L][4098][128] bf16 = 6,294,528 (from 71,814,592)
    bf16*  tab    = (bf16*)(ws + 71814592);        // ends 78,109,120

    PrepArgs pa = { conv1_w, conv2_w, int_lin_w, lin1_w, lin2_w,
                    c1t, c2t, ilt, l1t, l2t };
    prep_kernel<<<20, 256, 0, stream>>>(pa);
    table_kernel<<<LL * (NK + 1), 128, 0, stream>>>(mlp_w1, mlp_b1, mlp_w2, mlp_b2, tab);
    embed_kernel<<<NN * 16 / 256, 256, 0, stream>>>(x_atoms, embedding, h);

    // sort edges by dst (once; graph static across layers)
    hipMemsetAsync(d_hist, 0, NN * 4, stream);
    hist_kernel<<<(EE + 255) / 256, 256, 0, stream>>>(edge_index, d_hist);
    scan_kernel<<<1, 1024, 0, stream>>>(d_hist, d_rs, d_cur);
    scatter_kernel<<<(EE + 255) / 256, 256, 0, stream>>>(edge_attr, edge_index, d_cur,
                                                         d_sd, d_src);

    for (int l = 0; l < LL; l++) {
        xf_kernel<<<NBLK, 256, 0, stream>>>(h, c1t + l * FF * HH, xf);
        edge_kernel<<<NN / 4, 256, 0, stream>>>(d_sd, d_src, d_rs, d_hist, xf,
                                                tab + (size_t)l * 4098 * FF, agg);
        update_kernel<<<NBLK, 256, 0, stream>>>(agg, c2t + l * HH * FF, conv2_b + l * HH,
                                                ilt + l * HH * HH, int_lin_b + l * HH, h);
    }
    head_kernel<<<NBLK, 256, 0, stream>>>(h, l1t, lin1_b, l2t, lin2_b, partial);
    final_kernel<<<1, 64, 0, stream>>>(partial, readout_w, readout_b, (float*)d_out);
}

// Round 6
// 951.659 us; speedup vs baseline: 3.7732x; 1.1774x over previous
//
#include <hip/hip_runtime.h>
#include <hip/hip_bf16.h>
#include <math.h>

#define NN 50000
#define EE 800000
#define HH 128
#define FF 128
#define GG 50
#define LL 6
#define H2D 64
#define OUT_DIM 12
#define NK 1024          // table intervals; knots = NK+1, stride 1026 rows/layer
#define NBLK 782         // ceil(NN/64)
#define SB 196           // scan blocks: ceil(NN/256)

typedef __bf16 bf16;
typedef __attribute__((ext_vector_type(8))) __bf16 bf16x8;
typedef __attribute__((ext_vector_type(4))) float f32x4;
typedef __attribute__((ext_vector_type(2))) float f32x2;

#define DEV __device__ __forceinline__

DEV float sspf(float x) {
    return fmaxf(x, 0.f) + log1pf(__expf(-fabsf(x))) - 0.69314718055994531f;
}

DEV f32x4 mfma16(bf16x8 a, bf16x8 b, f32x4 c) {
    return __builtin_amdgcn_mfma_f32_16x16x32_bf16(a, b, c, 0, 0, 0);
}

DEV float blo(unsigned u) { return __uint_as_float(u << 16); }
DEV float bhi(unsigned u) { return __uint_as_float(u & 0xffff0000u); }

// -------- prep: transpose node-GEMM weights to [n][k] bf16 -------------------
struct PrepArgs {
    const float *conv1_w, *conv2_w, *int_lin_w, *lin1_w, *lin2_w;
    bf16 *c1t, *c2t, *ilt, *l1t, *l2t;
};

__global__ void prep_kernel(PrepArgs p) {
    int j = blockIdx.x;
    const float* src = nullptr; bf16* dst = nullptr; int R = 0, C = 0, K = 0;
    if (j < 18) {
        int l = j / 3, m = j % 3;
        switch (m) {
            case 0: src = p.conv1_w + l * HH * FF;   dst = p.c1t + l * FF * HH;  R = HH; C = FF; K = HH; break;
            case 1: src = p.conv2_w + l * FF * HH;   dst = p.c2t + l * HH * FF;  R = FF; C = HH; K = FF; break;
            case 2: src = p.int_lin_w + l * HH * HH; dst = p.ilt + l * HH * HH;  R = HH; C = HH; K = HH; break;
        }
    } else if (j == 18) { src = p.lin1_w; dst = p.l1t; R = HH;  C = H2D; K = HH; }
    else                { src = p.lin2_w; dst = p.l2t; R = H2D; C = H2D; K = H2D; }
    int total = C * K;
    for (int idx = threadIdx.x; idx < total; idx += blockDim.x) {
        int c = idx / K, r = idx - c * K;
        dst[idx] = (r < R) ? (bf16)src[r * C + c] : (bf16)0.f;
    }
}

// -------- filter table: T[l][r][:] = (ssp(gauss(d)@W1+b1)@W2+b2) * C(d) ------
__global__ __launch_bounds__(128) void table_kernel(const float* __restrict__ mlp_w1,
                                                    const float* __restrict__ mlp_b1,
                                                    const float* __restrict__ mlp_w2,
                                                    const float* __restrict__ mlp_b2,
                                                    bf16* __restrict__ tab) {
    int l = blockIdx.x / (NK + 1);
    int r = blockIdx.x % (NK + 1);
    float d = r * (10.f / NK);
    __shared__ float ed[GG];
    __shared__ float h1[FF];
    int f = threadIdx.x;
    const float step = 10.f / 49.f;
    const float coeff = -0.5f / (step * step);
    if (f < GG) {
        float diff = d - f * step;
        ed[f] = __expf(coeff * diff * diff);
    }
    __syncthreads();
    const float* W1 = mlp_w1 + l * GG * FF;
    float s = mlp_b1[l * FF + f];
    for (int g = 0; g < GG; g++) s += ed[g] * W1[g * FF + f];
    h1[f] = sspf(s);
    __syncthreads();
    const float* W2 = mlp_w2 + l * FF * FF;
    float s2 = mlp_b2[l * FF + f];
    for (int j = 0; j < FF; j++) s2 += h1[j] * W2[j * FF + f];
    float Cw = 0.5f * (cosf(d * 0.31415926535897932f) + 1.f);
    tab[((size_t)l * 1026 + r) * FF + f] = (bf16)(s2 * Cw);
}

// -------- edge sort by dst: histogram / hierarchical scan / scatter ----------
__global__ void hist_kernel(const int* __restrict__ eidx, int* __restrict__ hist) {
    int e = blockIdx.x * 256 + threadIdx.x;
    if (e < EE) atomicAdd(&hist[eidx[EE + e]], 1);
}

__global__ __launch_bounds__(256) void scanA_kernel(const int* __restrict__ hist,
                                                    int* __restrict__ bsum) {
    __shared__ int red[256];
    int t = threadIdx.x;
    int i = blockIdx.x * 256 + t;
    int v = (i < NN) ? hist[i] : 0;
    red[t] = v;
    __syncthreads();
    for (int off = 128; off > 0; off >>= 1) {
        if (t < off) red[t] += red[t + off];
        __syncthreads();
    }
    if (t == 0) bsum[blockIdx.x] = red[0];
}

__global__ __launch_bounds__(256) void scanB_kernel(int* __restrict__ bsum) {
    __shared__ int buf[256];
    int t = threadIdx.x;
    int v = (t < SB) ? bsum[t] : 0;
    buf[t] = v;
    __syncthreads();
    for (int off = 1; off < 256; off <<= 1) {
        int y = (t >= off) ? buf[t - off] : 0;
        __syncthreads();
        buf[t] += y;
        __syncthreads();
    }
    if (t < SB) bsum[t] = buf[t] - v;   // exclusive
}

__global__ __launch_bounds__(256) void scanC_kernel(const int* __restrict__ hist,
                                                    const int* __restrict__ bsum,
                                                    int* __restrict__ rs,
                                                    int* __restrict__ cur) {
    __shared__ int buf[256];
    int t = threadIdx.x;
    int i = blockIdx.x * 256 + t;
    int v = (i < NN) ? hist[i] : 0;
    buf[t] = v;
    __syncthreads();
    for (int off = 1; off < 256; off <<= 1) {
        int y = (t >= off) ? buf[t - off] : 0;
        __syncthreads();
        buf[t] += y;
        __syncthreads();
    }
    if (i < NN) {
        int ex = buf[t] - v + bsum[blockIdx.x];
        rs[i] = ex;
        cur[i] = ex;
    }
}

__global__ void scatter_kernel(const float* __restrict__ eattr, const int* __restrict__ eidx,
                               int* __restrict__ cur, float* __restrict__ d_sd,
                               int* __restrict__ d_src) {
    int e = blockIdx.x * 256 + threadIdx.x;
    if (e < EE) {
        int dd = eidx[EE + e];
        int pos = atomicAdd(&cur[dd], 1);
        d_sd[pos] = eattr[e];
        d_src[pos] = eidx[e];
    }
}

// -------- embed: h = embedding[x_atoms] (f32) --------------------------------
__global__ void embed_kernel(const int* __restrict__ x_atoms, const float* __restrict__ emb,
                             float* __restrict__ h) {
    int idx = blockIdx.x * blockDim.x + threadIdx.x;   // over NN*16
    if (idx >= NN * 16) return;
    int n = idx >> 4, ch = idx & 15;
    int a = x_atoms[n];
    const float* ep = emb + a * HH + ch * 8;
    f32x4 v0 = *(const f32x4*)ep;
    f32x4 v1 = *(const f32x4*)(ep + 4);
    float* hp = h + n * HH + ch * 8;
    *(f32x4*)hp = v0;
    *(f32x4*)(hp + 4) = v1;
}

// -------- xf = h @ conv1_w  (bf16 out, f32 h in) — layer 0 only --------------
__global__ __launch_bounds__(256) void xf_kernel(const float* __restrict__ h,
                                                 const bf16* __restrict__ c1t,
                                                 bf16* __restrict__ xf) {
    __shared__ bf16 sB[128 * 136];
    int tid = threadIdx.x;
    for (int idx = tid * 8; idx < 128 * 128; idx += 2048) {
        int n = idx >> 7, k = idx & 127;
        *(bf16x8*)&sB[n * 136 + k] = *(const bf16x8*)(c1t + idx);
    }
    int w = tid >> 6, lane = tid & 63, ln = lane & 15, kg = lane >> 4;
    int rowt = blockIdx.x * 64 + w * 16;
    int arow = min(rowt + ln, NN - 1);
    __syncthreads();
    f32x4 acc[8] = {};
#pragma unroll
    for (int k0 = 0; k0 < 128; k0 += 32) {
        const float* ap = h + arow * HH + k0 + kg * 8;
        f32x4 u0 = *(const f32x4*)ap;
        f32x4 u1 = *(const f32x4*)(ap + 4);
        bf16x8 a;
#pragma unroll
        for (int q = 0; q < 4; q++) { a[q] = (bf16)u0[q]; a[q + 4] = (bf16)u1[q]; }
#pragma unroll
        for (int t = 0; t < 8; t++) {
            bf16x8 b = *(const bf16x8*)&sB[(t * 16 + ln) * 136 + k0 + kg * 8];
            acc[t] = mfma16(a, b, acc[t]);
        }
    }
#pragma unroll
    for (int t = 0; t < 8; t++) {
        int colt = t * 16 + ln;
#pragma unroll
        for (int r = 0; r < 4; r++) {
            int orow = rowt + kg * 4 + r;
            if (orow < NN) xf[orow * FF + colt] = (bf16)acc[t][r];
        }
    }
}

// -------- edge kernel: CSR, one wave per node, no atomics --------------------
__global__ __launch_bounds__(256) void edge_kernel(const float* __restrict__ d_sd,
                                                   const int* __restrict__ d_src,
                                                   const int* __restrict__ d_rs,
                                                   const int* __restrict__ d_hist,
                                                   const bf16* __restrict__ xf,
                                                   const bf16* __restrict__ tab,
                                                   float* __restrict__ agg) {
    int tid = threadIdx.x;
    int w = tid >> 6, ln = tid & 63;
    int n = blockIdx.x * 4 + w;
    int start = d_rs[n], deg = d_hist[n];
    float a0 = 0.f, a1 = 0.f;
    for (int base = 0; base < deg; base += 64) {
        int cnt = min(deg - base, 64);
        float dv = 0.f; int sv = 0;
        if (ln < cnt) {
            dv = d_sd[start + base + ln];
            sv = d_src[start + base + ln];
        }
        float tt = dv * ((float)NK / 10.f);
        int   kv = (int)tt;
        float fv = tt - (float)kv;
#pragma unroll 2
        for (int j = 0; j < cnt; j++) {
            int   k  = __shfl(kv, j);
            float fr = __shfl(fv, j);
            int   s  = __shfl(sv, j);
            unsigned t0 = *(const unsigned*)(tab + k * FF + 2 * ln);
            unsigned t1 = *(const unsigned*)(tab + (k + 1) * FF + 2 * ln);
            unsigned xu = *(const unsigned*)(xf + s * FF + 2 * ln);
            float wa = fmaf(fr, blo(t1) - blo(t0), blo(t0));
            float wb = fmaf(fr, bhi(t1) - bhi(t0), bhi(t0));
            a0 = fmaf(wa, blo(xu), a0);
            a1 = fmaf(wb, bhi(xu), a1);
        }
    }
    f32x2 o; o[0] = a0; o[1] = a1;
    *(f32x2*)(agg + n * FF + 2 * ln) = o;
}

// -------- update (+fused next-layer xf) --------------------------------------
// h += ssp(agg@conv2+b) @ int_lin + b;  if c1t_next: xf = h_new @ conv1_next
__global__ __launch_bounds__(256) void update_kernel(const float* __restrict__ agg,
                                                     const bf16* __restrict__ c2t,
                                                     const float* __restrict__ c2b,
                                                     const bf16* __restrict__ ilt,
                                                     const float* __restrict__ ilb,
                                                     float* __restrict__ h,
                                                     const bf16* __restrict__ c1t_next,
                                                     bf16* __restrict__ xf) {
    __shared__ bf16 sB[128 * 136];
    __shared__ bf16 sT[64 * 136];
    int tid = threadIdx.x;
    for (int idx = tid * 8; idx < 128 * 128; idx += 2048) {
        int n = idx >> 7, k = idx & 127;
        *(bf16x8*)&sB[n * 136 + k] = *(const bf16x8*)(c2t + idx);
    }
    int w = tid >> 6, lane = tid & 63, ln = lane & 15, kg = lane >> 4;
    int rowt = blockIdx.x * 64 + w * 16;
    int arow = min(rowt + ln, NN - 1);
    __syncthreads();
    f32x4 acc[8] = {};
#pragma unroll
    for (int k0 = 0; k0 < 128; k0 += 32) {
        const float* ap = agg + arow * FF + k0 + kg * 8;
        f32x4 u0 = *(const f32x4*)ap;
        f32x4 u1 = *(const f32x4*)(ap + 4);
        bf16x8 a;
#pragma unroll
        for (int q = 0; q < 4; q++) { a[q] = (bf16)u0[q]; a[q + 4] = (bf16)u1[q]; }
#pragma unroll
        for (int t = 0; t < 8; t++) {
            bf16x8 b = *(const bf16x8*)&sB[(t * 16 + ln) * 136 + k0 + kg * 8];
            acc[t] = mfma16(a, b, acc[t]);
        }
    }
#pragma unroll
    for (int t = 0; t < 8; t++) {
        int colt = t * 16 + ln;
        float bb = c2b[colt];
#pragma unroll
        for (int r = 0; r < 4; r++)
            sT[(w * 16 + kg * 4 + r) * 136 + colt] = (bf16)sspf(acc[t][r] + bb);
    }
    __syncthreads();   // all GEMM1 reads of sB done, sT visible
    // restage sB with int_lin weights
    for (int idx = tid * 8; idx < 128 * 128; idx += 2048) {
        int n = idx >> 7, k = idx & 127;
        *(bf16x8*)&sB[n * 136 + k] = *(const bf16x8*)(ilt + idx);
    }
    __syncthreads();
    f32x4 acc2[8] = {};
#pragma unroll
    for (int k0 = 0; k0 < 128; k0 += 32) {
        bf16x8 a = *(const bf16x8*)&sT[(w * 16 + ln) * 136 + k0 + kg * 8];
#pragma unroll
        for (int t = 0; t < 8; t++) {
            bf16x8 b = *(const bf16x8*)&sB[(t * 16 + ln) * 136 + k0 + kg * 8];
            acc2[t] = mfma16(a, b, acc2[t]);
        }
    }
    // epilogue: h_new -> global (+ sT bf16 strip for fused xf; own rows only)
#pragma unroll
    for (int t = 0; t < 8; t++) {
        int colt = t * 16 + ln;
        float bb = ilb[colt];
#pragma unroll
        for (int r = 0; r < 4; r++) {
            int orow = rowt + kg * 4 + r;
            float hn = 0.f;
            if (orow < NN) {
                hn = h[orow * HH + colt] + acc2[t][r] + bb;
                h[orow * HH + colt] = hn;
            }
            if (c1t_next) sT[(w * 16 + kg * 4 + r) * 136 + colt] = (bf16)hn;
        }
    }
    if (c1t_next) {
        __syncthreads();   // GEMM2 reads of sB done everywhere; sT strips visible
        for (int idx = tid * 8; idx < 128 * 128; idx += 2048) {
            int n2 = idx >> 7, k2 = idx & 127;
            *(bf16x8*)&sB[n2 * 136 + k2] = *(const bf16x8*)(c1t_next + idx);
        }
        __syncthreads();
        f32x4 acc3[8] = {};
#pragma unroll
        for (int k0 = 0; k0 < 128; k0 += 32) {
            bf16x8 a = *(const bf16x8*)&sT[(w * 16 + ln) * 136 + k0 + kg * 8];
#pragma unroll
            for (int t = 0; t < 8; t++) {
                bf16x8 b = *(const bf16x8*)&sB[(t * 16 + ln) * 136 + k0 + kg * 8];
                acc3[t] = mfma16(a, b, acc3[t]);
            }
        }
#pragma unroll
        for (int t = 0; t < 8; t++) {
            int colt = t * 16 + ln;
#pragma unroll
            for (int r = 0; r < 4; r++) {
                int orow = rowt + kg * 4 + r;
                if (orow < NN) xf[orow * FF + colt] = (bf16)acc3[t][r];
            }
        }
    }
}

// -------- head: per-block partial sums of (ssp(h@lin1+b)@lin2+b) -------------
__global__ __launch_bounds__(256) void head_kernel(const float* __restrict__ h,
                                                   const bf16* __restrict__ l1t,
                                                   const float* __restrict__ l1b,
                                                   const bf16* __restrict__ l2t,
                                                   const float* __restrict__ l2b,
                                                   float* __restrict__ partial) {
    __shared__ bf16 sB1[64 * 136];
    __shared__ bf16 sB2[64 * 72];
    __shared__ bf16 sT[64 * 72];
    float* sPart = (float*)sT;            // reused after barrier: [4][64] f32
    int tid = threadIdx.x;
    for (int idx = tid * 8; idx < 64 * 128; idx += 2048) {
        int n = idx >> 7, k = idx & 127;
        *(bf16x8*)&sB1[n * 136 + k] = *(const bf16x8*)(l1t + idx);
    }
    for (int idx = tid * 8; idx < 64 * 64; idx += 2048) {
        int n = idx >> 6, k = idx & 63;
        *(bf16x8*)&sB2[n * 72 + k] = *(const bf16x8*)(l2t + idx);
    }
    int w = tid >> 6, lane = tid & 63, ln = lane & 15, kg = lane >> 4;
    int rowt = blockIdx.x * 64 + w * 16;
    int arow = min(rowt + ln, NN - 1);
    __syncthreads();
    f32x4 acc[4] = {};
#pragma unroll
    for (int k0 = 0; k0 < 128; k0 += 32) {
        const float* ap = h + arow * HH + k0 + kg * 8;
        f32x4 u0 = *(const f32x4*)ap;
        f32x4 u1 = *(const f32x4*)(ap + 4);
        bf16x8 a;
#pragma unroll
        for (int q = 0; q < 4; q++) { a[q] = (bf16)u0[q]; a[q + 4] = (bf16)u1[q]; }
#pragma unroll
        for (int t = 0; t < 4; t++) {
            bf16x8 b = *(const bf16x8*)&sB1[(t * 16 + ln) * 136 + k0 + kg * 8];
            acc[t] = mfma16(a, b, acc[t]);
        }
    }
#pragma unroll
    for (int t = 0; t < 4; t++) {
        int colt = t * 16 + ln;
        float bb = l1b[colt];
#pragma unroll
        for (int r = 0; r < 4; r++)
            sT[(w * 16 + kg * 4 + r) * 72 + colt] = (bf16)sspf(acc[t][r] + bb);
    }
    __syncthreads();
    f32x4 acc2[4] = {};
#pragma unroll
    for (int k0 = 0; k0 < 64; k0 += 32) {
        bf16x8 a = *(const bf16x8*)&sT[(w * 16 + ln) * 72 + k0 + kg * 8];
#pragma unroll
        for (int t = 0; t < 4; t++) {
            bf16x8 b = *(const bf16x8*)&sB2[(t * 16 + ln) * 72 + k0 + kg * 8];
            acc2[t] = mfma16(a, b, acc2[t]);
        }
    }
    __syncthreads();   // all GEMM2 reads of sT done; safe to reuse as sPart
#pragma unroll
    for (int t = 0; t < 4; t++) {
        int colt = t * 16 + ln;
        float bb = l2b[colt];
        float v = 0.f;
#pragma unroll
        for (int r = 0; r < 4; r++) {
            int orow = rowt + kg * 4 + r;
            if (orow < NN) v += acc2[t][r] + bb;
        }
        v += __shfl_xor(v, 16);
        v += __shfl_xor(v, 32);
        if (kg == 0) sPart[w * 64 + colt] = v;
    }
    __syncthreads();
    if (tid < 64) {
        float s = sPart[tid] + sPart[64 + tid] + sPart[128 + tid] + sPart[192 + tid];
        partial[blockIdx.x * 64 + tid] = s;
    }
}

__global__ __launch_bounds__(64) void final_kernel(const float* __restrict__ partial,
                                                   const float* __restrict__ rw,
                                                   const float* __restrict__ rb,
                                                   float* __restrict__ out) {
    __shared__ float sv[64];
    int j = threadIdx.x;
    float s = 0.f;
    for (int b = 0; b < NBLK; b++) s += partial[b * 64 + j];
    sv[j] = s;
    __syncthreads();
    if (j < OUT_DIM) {
        float o = rb[j];
        for (int i = 0; i < H2D; i++) o += sv[i] * rw[i * OUT_DIM + j];
        out[j] = o;
    }
}

// -------- launch -------------------------------------------------------------
extern "C" void kernel_launch(void* const* d_in, const int* in_sizes, int n_in,
                              void* d_out, int out_size, void* d_ws, size_t ws_size,
                              hipStream_t stream) {
    const int*   x_atoms    = (const int*)d_in[0];
    const int*   edge_index = (const int*)d_in[1];
    const float* edge_attr  = (const float*)d_in[2];
    const float* embedding  = (const float*)d_in[3];
    const float* mlp_w1     = (const float*)d_in[4];
    const float* mlp_b1     = (const float*)d_in[5];
    const float* mlp_w2     = (const float*)d_in[6];
    const float* mlp_b2     = (const float*)d_in[7];
    const float* conv1_w    = (const float*)d_in[8];
    const float* conv2_w    = (const float*)d_in[9];
    const float* conv2_b    = (const float*)d_in[10];
    const float* int_lin_w  = (const float*)d_in[11];
    const float* int_lin_b  = (const float*)d_in[12];
    const float* lin1_w     = (const float*)d_in[13];
    const float* lin1_b     = (const float*)d_in[14];
    const float* lin2_w     = (const float*)d_in[15];
    const float* lin2_b     = (const float*)d_in[16];
    const float* readout_w  = (const float*)d_in[17];
    const float* readout_b  = (const float*)d_in[18];

    char* ws = (char*)d_ws;
    float* h       = (float*)(ws + 0);             // 25,600,000
    bf16*  xf      = (bf16*)(ws + 25600000);       // 12,800,000
    float* agg     = (float*)(ws + 38400000);      // 25,600,000
    float* partial = (float*)(ws + 64000000);      // 200,192 (782*64*4)
    size_t wb = 64200192;
    bf16* c1t = (bf16*)(ws + wb);                  // 196,608
    bf16* c2t = (bf16*)(ws + wb + 196608);
    bf16* ilt = (bf16*)(ws + wb + 393216);
    bf16* l1t = (bf16*)(ws + wb + 589824);         // 16,384
    bf16* l2t = (bf16*)(ws + wb + 606208);         // 8,192
    // sort scratch (from 64,814,592)
    int*   d_hist = (int*)(ws + 64814592);         // 200,000
    int*   d_rs   = (int*)(ws + 65014592);         // 200,000
    int*   d_cur  = (int*)(ws + 65214592);         // 200,000
    int*   d_bsum = (int*)(ws + 65414592);         // 1,024
    float* d_sd   = (float*)(ws + 65415616);       // 3,200,000
    int*   d_src  = (int*)(ws + 68615616);         // 3,200,000
    // filter tables: [L][1026][128] bf16 = 1,575,936 (from 71,815,616)
    bf16*  tab    = (bf16*)(ws + 71815616);        // ends 73,391,552

    PrepArgs pa = { conv1_w, conv2_w, int_lin_w, lin1_w, lin2_w,
                    c1t, c2t, ilt, l1t, l2t };
    prep_kernel<<<20, 256, 0, stream>>>(pa);
    table_kernel<<<LL * (NK + 1), 128, 0, stream>>>(mlp_w1, mlp_b1, mlp_w2, mlp_b2, tab);
    embed_kernel<<<NN * 16 / 256, 256, 0, stream>>>(x_atoms, embedding, h);

    // sort edges by dst (once; graph static across layers)
    hipMemsetAsync(d_hist, 0, NN * 4, stream);
    hist_kernel<<<(EE + 255) / 256, 256, 0, stream>>>(edge_index, d_hist);
    scanA_kernel<<<SB, 256, 0, stream>>>(d_hist, d_bsum);
    scanB_kernel<<<1, 256, 0, stream>>>(d_bsum);
    scanC_kernel<<<SB, 256, 0, stream>>>(d_hist, d_bsum, d_rs, d_cur);
    scatter_kernel<<<(EE + 255) / 256, 256, 0, stream>>>(edge_attr, edge_index, d_cur,
                                                         d_sd, d_src);

    xf_kernel<<<NBLK, 256, 0, stream>>>(h, c1t, xf);   // layer 0 xf
    for (int l = 0; l < LL; l++) {
        edge_kernel<<<NN / 4, 256, 0, stream>>>(d_sd, d_src, d_rs, d_hist, xf,
                                                tab + (size_t)l * 1026 * FF, agg);
        const bf16* c1n = (l + 1 < LL) ? (c1t + (size_t)(l + 1) * FF * HH) : nullptr;
        update_kernel<<<NBLK, 256, 0, stream>>>(agg, c2t + l * HH * FF, conv2_b + l * HH,
                                                ilt + l * HH * HH, int_lin_b + l * HH, h,
                                                c1n, xf);
    }
    head_kernel<<<NBLK, 256, 0, stream>>>(h, l1t, lin1_b, l2t, lin2_b, partial);
    final_kernel<<<1, 64, 0, stream>>>(partial, readout_w, readout_b, (float*)d_out);
}